// Round 11
// baseline (982.172 us; speedup 1.0000x reference)
//
#include <hip/hip_runtime.h>
#include <hip/hip_bf16.h>

#define NB 64
#define T1 3136
#define T2 784
#define T3 196
#define D1 147
#define D2 576

#define KP1 160   // padded K for front1 W^T (147 -> 160)
#define KS1 168   // front1 LDS A row stride (bf16)
#define KS2 584   // front2/final LDS A row stride (bf16)
#define KQ2 72    // kq bf16 row stride (144B, 16B-aligned; 36dw = 4 mod 32)

typedef __attribute__((ext_vector_type(8))) short bf16x8;
typedef __attribute__((ext_vector_type(4))) float f32x4;

__device__ __forceinline__ unsigned short f2bf(float v) {
    unsigned int u = __float_as_uint(v);
    return (unsigned short)((u + 0x7FFFu + ((u >> 16) & 1u)) >> 16);
}

__device__ __forceinline__ float waveReduceSum(float v) {
#pragma unroll
    for (int off = 32; off > 0; off >>= 1) v += __shfl_down(v, off, 64);
    return __shfl(v, 0, 64);
}

// ---------------------------------------------------------------------------
// prep_sums (parallel, 16-row chunks + atomics into pre-zeroed s2/s3).
// prep_wt: split-bf16 W^T in PACKED tile layout (1KB per (16-col tile, 32-K)).
// prep_rf: same packing for rf (N=32, K=64) -- B operand of the prm MFMA.
// ---------------------------------------------------------------------------
__global__ __launch_bounds__(192) void prep_sums(
    const float* __restrict__ w, const float* __restrict__ g,
    const float* __restrict__ bb, const float* __restrict__ kqvb,
    float* __restrict__ s2, float* __restrict__ s3, int D)
{
    const int col = threadIdx.x;
    const int d0 = blockIdx.x * 16;
    const int d1 = (d0 + 16 < D) ? d0 + 16 : D;
    float a2 = 0.f, a3 = 0.f;
    for (int d = d0; d < d1; ++d) {
        const float wv = w[d * 192 + col];
        a2 += wv * g[d];
        a3 += wv * bb[d];
    }
    if (blockIdx.x == 0) a3 += kqvb[col];
    atomicAdd(&s2[col], a2);
    atomicAdd(&s3[col], a3);
}

__global__ __launch_bounds__(256) void prep_wt(
    const float* __restrict__ w, const float* __restrict__ g,
    unsigned short* __restrict__ hi, unsigned short* __restrict__ lo,
    int D, int K, int N)
{
    const int i = blockIdx.x * 256 + threadIdx.x;
    if (i >= N * K) return;
    const int n = i / K, k = i % K;
    const float v = (k < D) ? w[k * N + n] * (g ? g[k] : 1.f) : 0.f;
    const unsigned short h = f2bf(v);
    const float hf = __uint_as_float((unsigned int)h << 16);
    const size_t pidx = (size_t)((n >> 4) * (K >> 5) + (k >> 5)) * 512
                      + (size_t)((((k >> 3) & 3) * 16 + (n & 15)) * 8 + (k & 7));
    hi[pidx] = h;
    lo[pidx] = f2bf(v - hf);
}

__global__ __launch_bounds__(256) void prep_rf(
    const float* __restrict__ rf,              // (32,64) row n, col k
    unsigned short* __restrict__ hi, unsigned short* __restrict__ lo)
{
    const int i = blockIdx.x * 256 + threadIdx.x;
    if (i >= 2048) return;
    const int n = i >> 6, k = i & 63;
    const float v = rf[i];
    const unsigned short h = f2bf(v);
    const float hf = __uint_as_float((unsigned int)h << 16);
    const int pidx = ((n >> 4) * 2 + (k >> 5)) * 512
                   + ((((k >> 3) & 3) * 16 + (n & 15)) * 8 + (k & 7));
    hi[pidx] = h;
    lo[pidx] = f2bf(v - hf);
}

// ---------------------------------------------------------------------------
// front1 v8 (full MFMA): 32 tokens, 256 thr = 4 waves.
// (a) fill remapped to (m=tid>>3, j=tid&7): LDS write banks 2-way (free) vs
//     R10's 4-way (the 8.3M conflict cycles -- identical R8 vs R10 -- were
//     fill writes, not the xd pass), 8-lane d-contiguous global reads.
// (b) prm_exp now split-bf16 MFMA: kq stored post-fold as bf16 hi/lo in LDS
//     (aliases dead A-buffer), rf packed as B; xd from registers during
//     scatter via 16-lane shfl_xor; exp + coalesced store from C frags.
//     Removes 512 MAC + 128 b128-reads per thread and the 64-VGPR rfr array.
// ---------------------------------------------------------------------------
__global__ __launch_bounds__(256) void front1(
    const float* __restrict__ x,
    const unsigned short* __restrict__ wt_hi,  // packed (192,KP1)
    const unsigned short* __restrict__ wt_lo,
    const float* __restrict__ s2v, const float* __restrict__ s3v,
    const unsigned short* __restrict__ rf_hi,  // packed (32,64)
    const unsigned short* __restrict__ rf_lo,
    float* __restrict__ kp, float* __restrict__ qp,
    float* __restrict__ v_out)
{
    const int tok0 = blockIdx.x * 32;
    const int b = tok0 / T1;
    const int tbase = tok0 % T1;
    const int tid = threadIdx.x;
    const int wv = tid >> 6, l = tid & 63;
    const int l15 = l & 15, lg = l >> 4;

    __shared__ __align__(16) unsigned short Abuf[2 * 32 * KS1];  // 21504B
    __shared__ float ps_sum[256], ps_sq[256];
    __shared__ float mu_s[32], rs_s[32], xd_s[64];

    unsigned short* A_hi = Abuf;
    unsigned short* A_lo = Abuf + 32 * KS1;
    unsigned short* kqh = Abuf;                // [64][KQ2], aliases post-barrier B
    unsigned short* kql = Abuf + 64 * KQ2;     // 18432B total <= 21504

    // --- fill: m = tid>>3 (token), j = tid&7 (d-slice) ---
    { const int m = tid >> 3, j = tid & 7;
      const int t = tbase + m;
      const int py = t / 56, px = t % 56;
      const int iy0 = py * 4 - 2, ix0 = px * 4 - 2;
      float sm = 0.f, sq = 0.f;
      for (int d = j; d < KS1; d += 8) {
          float val = 0.f;
          if (d < D1) {
              const int cc = d / 49, r = d % 49, ki = r / 7, kj = r % 7;
              const int iy = iy0 + ki, ix = ix0 + kj;
              if (iy >= 0 && iy < 224 && ix >= 0 && ix < 224)
                  val = x[((b * 3 + cc) * 224 + iy) * 224 + ix];
          }
          sm += val; sq += val * val;
          const unsigned short h = f2bf(val);
          A_hi[m * KS1 + d] = h;
          A_lo[m * KS1 + d] = f2bf(val - __uint_as_float((unsigned int)h << 16));
      }
      ps_sum[tid] = sm; ps_sq[tid] = sq; }
    __syncthreads();                           // barrier A
    if (tid < 32) {
        float s = 0.f, s2 = 0.f;
#pragma unroll
        for (int j2 = 0; j2 < 8; ++j2) { s += ps_sum[tid*8+j2]; s2 += ps_sq[tid*8+j2]; }
        const float mu = s * (1.f / D1);
        mu_s[tid] = mu; rs_s[tid] = rsqrtf(s2 * (1.f / D1) - mu * mu + 1e-5f);
    }

    // --- MFMA matvec: wave wv owns N-tiles {3wv..3wv+2} x M-tiles {0,1} ---
    f32x4 acc[2][3];
    { const f32x4 z = {0.f, 0.f, 0.f, 0.f};
#pragma unroll
      for (int mt = 0; mt < 2; ++mt)
#pragma unroll
        for (int nt = 0; nt < 3; ++nt) acc[mt][nt] = z; }

    for (int ks = 0; ks < 5; ++ks) {
        const int ko = ks * 32 + 8 * lg;
        const bf16x8 ah0 = *(const bf16x8*)&A_hi[l15 * KS1 + ko];
        const bf16x8 ah1 = *(const bf16x8*)&A_hi[(16 + l15) * KS1 + ko];
        const bf16x8 al0 = *(const bf16x8*)&A_lo[l15 * KS1 + ko];
        const bf16x8 al1 = *(const bf16x8*)&A_lo[(16 + l15) * KS1 + ko];
#pragma unroll
        for (int nt = 0; nt < 3; ++nt) {
            const size_t wo = ((size_t)((3 * wv + nt) * 5 + ks) << 9) + (size_t)(l << 3);
            const bf16x8 bh = *(const bf16x8*)&wt_hi[wo];
            const bf16x8 bl = *(const bf16x8*)&wt_lo[wo];
            acc[0][nt] = __builtin_amdgcn_mfma_f32_16x16x32_bf16(ah0, bh, acc[0][nt], 0, 0, 0);
            acc[1][nt] = __builtin_amdgcn_mfma_f32_16x16x32_bf16(ah1, bh, acc[1][nt], 0, 0, 0);
            acc[0][nt] = __builtin_amdgcn_mfma_f32_16x16x32_bf16(al0, bh, acc[0][nt], 0, 0, 0);
            acc[1][nt] = __builtin_amdgcn_mfma_f32_16x16x32_bf16(al1, bh, acc[1][nt], 0, 0, 0);
            acc[0][nt] = __builtin_amdgcn_mfma_f32_16x16x32_bf16(ah0, bl, acc[0][nt], 0, 0, 0);
            acc[1][nt] = __builtin_amdgcn_mfma_f32_16x16x32_bf16(ah1, bl, acc[1][nt], 0, 0, 0);
        }
    }
    __syncthreads();                           // barrier B: Abuf dead, mu_s ready

    // --- fold-correction + scatter (kq -> bf16 split LDS, v -> global) ---
    float xk[2][4], xq[2][4];
#pragma unroll
    for (int mt = 0; mt < 2; ++mt)
#pragma unroll
        for (int r = 0; r < 4; ++r) { xk[mt][r] = 0.f; xq[mt][r] = 0.f; }

#pragma unroll
    for (int nt = 0; nt < 3; ++nt) {
        const int col = 48 * wv + 16 * nt + l15;
        const int third = col >> 6, cc = col & 63;
        const float s2c = s2v[col], s3c = s3v[col];
#pragma unroll
        for (int mt = 0; mt < 2; ++mt) {
#pragma unroll
            for (int r = 0; r < 4; ++r) {
                const int token = mt * 16 + 4 * lg + r;
                const float o = rs_s[token] * (acc[mt][nt][r] - mu_s[token] * s2c) + s3c;
                if (third == 2) {
                    v_out[(size_t)(tok0 + token) * 64 + cc] = o;
                } else {
                    const int row = third * 32 + token;
                    const unsigned short h = f2bf(o);
                    kqh[row * KQ2 + cc] = h;
                    kql[row * KQ2 + cc] = f2bf(o - __uint_as_float((unsigned int)h << 16));
                    if (third == 0) xk[mt][r] += o * o; else xq[mt][r] += o * o;
                }
            }
        }
    }
    // xd partials: reduce over l15 (16-lane groups), stash per-wave in ps_sum
#pragma unroll
    for (int mt = 0; mt < 2; ++mt) {
#pragma unroll
        for (int r = 0; r < 4; ++r) {
            float a = xk[mt][r], q2 = xq[mt][r];
#pragma unroll
            for (int off = 1; off < 16; off <<= 1) {
                a  += __shfl_xor(a,  off, 64);
                q2 += __shfl_xor(q2, off, 64);
            }
            if (l15 == 0) {
                const int token = mt * 16 + 4 * lg + r;
                ps_sum[wv * 64 + token]      = a;
                ps_sum[wv * 64 + 32 + token] = q2;
            }
        }
    }
    __syncthreads();                           // barrier C: kq LDS + partials ready
    if (tid < 64)
        xd_s[tid] = 0.5f * (ps_sum[tid] + ps_sum[64+tid] + ps_sum[128+tid] + ps_sum[192+tid]);
    __syncthreads();                           // barrier D

    // --- prm_exp via MFMA: A = kq[64][64], B = rf[32][64]; wave wv = M-tile ---
    f32x4 pacc[2];
    { const f32x4 z = {0.f, 0.f, 0.f, 0.f}; pacc[0] = z; pacc[1] = z; }
#pragma unroll
    for (int ks = 0; ks < 2; ++ks) {
        const int ko = ks * 32 + 8 * lg;
        const bf16x8 ah = *(const bf16x8*)&kqh[(16 * wv + l15) * KQ2 + ko];
        const bf16x8 al = *(const bf16x8*)&kql[(16 * wv + l15) * KQ2 + ko];
#pragma unroll
        for (int nt = 0; nt < 2; ++nt) {
            const int wo = (nt * 2 + ks) * 512 + l * 8;
            const bf16x8 bh = *(const bf16x8*)&rf_hi[wo];
            const bf16x8 bl = *(const bf16x8*)&rf_lo[wo];
            pacc[nt] = __builtin_amdgcn_mfma_f32_16x16x32_bf16(ah, bh, pacc[nt], 0, 0, 0);
            pacc[nt] = __builtin_amdgcn_mfma_f32_16x16x32_bf16(al, bh, pacc[nt], 0, 0, 0);
            pacc[nt] = __builtin_amdgcn_mfma_f32_16x16x32_bf16(ah, bl, pacc[nt], 0, 0, 0);
        }
    }
#pragma unroll
    for (int nt = 0; nt < 2; ++nt) {
#pragma unroll
        for (int r = 0; r < 4; ++r) {
            const int row = 16 * wv + 4 * lg + r;
            const int half = row >> 5, token = row & 31;
            const float p = expf(pacc[nt][r] - xd_s[row]) * 0.1767766952966369f;
            (half ? qp : kp)[(size_t)(tok0 + token) * 32 + nt * 16 + l15] = p;
        }
    }
}

// ---------------------------------------------------------------------------
// front2 v6 (full MFMA): 16 tokens, 128 thr = 2 waves. Same prm-MFMA + reg-xd
// restructure as front1.
// ---------------------------------------------------------------------------
__global__ __launch_bounds__(128) void front2(
    const float* __restrict__ src,             // o1 (B*T1,64)
    const unsigned short* __restrict__ wt_hi,  // packed (192,576)
    const unsigned short* __restrict__ wt_lo,
    const float* __restrict__ s2v, const float* __restrict__ s3v,
    const unsigned short* __restrict__ rf_hi,  // packed (32,64)
    const unsigned short* __restrict__ rf_lo,
    float* __restrict__ kp, float* __restrict__ qp,
    float* __restrict__ v_out)
{
    const int tok0 = blockIdx.x * 16;
    const int b = tok0 / T2;
    const int tbase = tok0 % T2;
    const int tid = threadIdx.x;
    const int wv = tid >> 6, l = tid & 63;
    const int l15 = l & 15, lg = l >> 4;

    __shared__ __align__(16) unsigned short Abuf[2 * 16 * KS2];  // 37376B
    __shared__ float ps_sum[128], ps_sq[128];
    __shared__ float mu_s[16], rs_s[16], xd_s[32];

    unsigned short* A_hi = Abuf;
    unsigned short* A_lo = Abuf + 16 * KS2;
    unsigned short* kqh = Abuf;                // [32][KQ2], aliases post-barrier B
    unsigned short* kql = Abuf + 32 * KQ2;

    // --- fill: thread owns (token g16, channel-slice ch); 72 values ---
    { const int g16 = tid >> 3, ch = tid & 7;
      const int tmine = tbase + g16;
      const int py = tmine / 28, px = tmine % 28;
      const int iy0 = py * 2 - 1, ix0 = px * 2 - 1;
      const float* srcb = src + (size_t)b * T1 * 64 + ch;
      unsigned short* Ah = &A_hi[g16 * KS2];
      unsigned short* Al = &A_lo[g16 * KS2];
      float sm = 0.f, sq = 0.f;
#pragma unroll
      for (int r = 0; r < 9; ++r) {
          const int iy = iy0 + r / 3, ix = ix0 + r % 3;
          const bool ok = (iy >= 0 && iy < 56 && ix >= 0 && ix < 56);
          const float* sp = srcb + (size_t)(iy * 56 + ix) * 64;
#pragma unroll
          for (int c = 0; c < 8; ++c) {
              const float val = ok ? sp[c * 8] : 0.f;
              sm += val; sq += val * val;
              const int d = (c * 8 + ch) * 9 + r;
              const unsigned short h = f2bf(val);
              Ah[d] = h;
              Al[d] = f2bf(val - __uint_as_float((unsigned int)h << 16));
          }
      }
      ps_sum[tid] = sm; ps_sq[tid] = sq; }
    __syncthreads();                           // barrier A
    if (tid < 16) {
        float s = 0.f, s2 = 0.f;
#pragma unroll
        for (int j = 0; j < 8; ++j) { s += ps_sum[tid*8+j]; s2 += ps_sq[tid*8+j]; }
        const float mu = s * (1.f / D2);
        mu_s[tid] = mu; rs_s[tid] = rsqrtf(s2 * (1.f / D2) - mu * mu + 1e-5f);
    }

    // --- MFMA: wave wv owns cols [96wv, 96wv+96) via 6 N-tiles ---
    f32x4 acc[6];
    { const f32x4 z = {0.f, 0.f, 0.f, 0.f};
#pragma unroll
      for (int nt = 0; nt < 6; ++nt) acc[nt] = z; }

    for (int ks = 0; ks < 18; ++ks) {
        const int ko = ks * 32 + 8 * lg;
        const bf16x8 ah = *(const bf16x8*)&A_hi[l15 * KS2 + ko];
        const bf16x8 al = *(const bf16x8*)&A_lo[l15 * KS2 + ko];
#pragma unroll
        for (int nt = 0; nt < 6; ++nt) {
            const size_t wo = ((size_t)((6 * wv + nt) * 18 + ks) << 9) + (size_t)(l << 3);
            const bf16x8 bh = *(const bf16x8*)&wt_hi[wo];
            const bf16x8 bl = *(const bf16x8*)&wt_lo[wo];
            acc[nt] = __builtin_amdgcn_mfma_f32_16x16x32_bf16(ah, bh, acc[nt], 0, 0, 0);
            acc[nt] = __builtin_amdgcn_mfma_f32_16x16x32_bf16(al, bh, acc[nt], 0, 0, 0);
            acc[nt] = __builtin_amdgcn_mfma_f32_16x16x32_bf16(ah, bl, acc[nt], 0, 0, 0);
        }
    }
    __syncthreads();                           // barrier B: Abuf dead, mu_s ready

    // --- fold-correction + scatter (kq -> bf16 split LDS, v -> global) ---
    float xk[4], xq[4];
#pragma unroll
    for (int r = 0; r < 4; ++r) { xk[r] = 0.f; xq[r] = 0.f; }

#pragma unroll
    for (int nt = 0; nt < 6; ++nt) {
        const int col = 96 * wv + 16 * nt + l15;
        const int third = col >> 6, cc = col & 63;
        const float s2c = s2v[col], s3c = s3v[col];
#pragma unroll
        for (int r = 0; r < 4; ++r) {
            const int token = 4 * lg + r;
            const float o = rs_s[token] * (acc[nt][r] - mu_s[token] * s2c) + s3c;
            if (third == 2) {
                v_out[(size_t)(tok0 + token) * 64 + cc] = o;
            } else {
                const int row = third * 16 + token;
                const unsigned short h = f2bf(o);
                kqh[row * KQ2 + cc] = h;
                kql[row * KQ2 + cc] = f2bf(o - __uint_as_float((unsigned int)h << 16));
                if (third == 0) xk[r] += o * o; else xq[r] += o * o;
            }
        }
    }
#pragma unroll
    for (int r = 0; r < 4; ++r) {
        float a = xk[r], q2 = xq[r];
#pragma unroll
        for (int off = 1; off < 16; off <<= 1) {
            a  += __shfl_xor(a,  off, 64);
            q2 += __shfl_xor(q2, off, 64);
        }
        if (l15 == 0) {
            const int token = 4 * lg + r;
            ps_sum[wv * 32 + token]      = a;
            ps_sum[wv * 32 + 16 + token] = q2;
        }
    }
    __syncthreads();                           // barrier C
    if (tid < 32)
        xd_s[tid] = 0.5f * (ps_sum[tid] + ps_sum[32 + tid]);
    __syncthreads();                           // barrier D

    // --- prm_exp via MFMA: A = kq[32][64], B = rf[32][64]; wave wv = M-tile ---
    f32x4 pacc[2];
    { const f32x4 z = {0.f, 0.f, 0.f, 0.f}; pacc[0] = z; pacc[1] = z; }
#pragma unroll
    for (int ks = 0; ks < 2; ++ks) {
        const int ko = ks * 32 + 8 * lg;
        const bf16x8 ah = *(const bf16x8*)&kqh[(16 * wv + l15) * KQ2 + ko];
        const bf16x8 al = *(const bf16x8*)&kql[(16 * wv + l15) * KQ2 + ko];
#pragma unroll
        for (int nt = 0; nt < 2; ++nt) {
            const int wo = (nt * 2 + ks) * 512 + l * 8;
            const bf16x8 bh = *(const bf16x8*)&rf_hi[wo];
            const bf16x8 bl = *(const bf16x8*)&rf_lo[wo];
            pacc[nt] = __builtin_amdgcn_mfma_f32_16x16x32_bf16(ah, bh, pacc[nt], 0, 0, 0);
            pacc[nt] = __builtin_amdgcn_mfma_f32_16x16x32_bf16(al, bh, pacc[nt], 0, 0, 0);
            pacc[nt] = __builtin_amdgcn_mfma_f32_16x16x32_bf16(ah, bl, pacc[nt], 0, 0, 0);
        }
    }
#pragma unroll
    for (int nt = 0; nt < 2; ++nt) {
#pragma unroll
        for (int r = 0; r < 4; ++r) {
            const int row = 16 * wv + 4 * lg + r;
            const int half = row >> 4, token = row & 15;
            const float p = expf(pacc[nt][r] - xd_s[row]) * 0.1767766952966369f;
            (half ? qp : kp)[(size_t)(tok0 + token) * 32 + nt * 16 + l15] = p;
        }
    }
}

// ---------------------------------------------------------------------------
// reduce_kv, split S-ways over T with atomics (ksum/kptv pre-zeroed)
// ---------------------------------------------------------------------------
template <int T, int S>
__global__ __launch_bounds__(256) void reduce_kv(
    const float* __restrict__ kp, const float* __restrict__ v,
    float* __restrict__ ksum, float* __restrict__ kptv)
{
    const int b = blockIdx.x / S, s = blockIdx.x % S;
    const int chunk = T / S;
    const int tid = threadIdx.x;
    __shared__ float kp_s[8][32];
    __shared__ float v_s[8][64];
    float acc[8] = {0.f, 0.f, 0.f, 0.f, 0.f, 0.f, 0.f, 0.f};
    float ks = 0.f;
    const int n = tid >> 2;
    const int mb = (tid & 3) * 8;
    const float* kpb = kp + (size_t)b * T * 32;
    const float* vb  = v  + (size_t)b * T * 64;

    for (int t0 = s * chunk; t0 < (s + 1) * chunk; t0 += 8) {
        kp_s[tid >> 5][tid & 31] = kpb[(t0 + (tid >> 5)) * 32 + (tid & 31)];
        {
            const int i0 = tid * 2, i1 = tid * 2 + 1;
            v_s[i0 >> 6][i0 & 63] = vb[(t0 + (i0 >> 6)) * 64 + (i0 & 63)];
            v_s[i1 >> 6][i1 & 63] = vb[(t0 + (i1 >> 6)) * 64 + (i1 & 63)];
        }
        __syncthreads();
#pragma unroll
        for (int tt = 0; tt < 8; ++tt) {
            const float vv = v_s[tt][n];
#pragma unroll
            for (int i = 0; i < 8; ++i) acc[i] += vv * kp_s[tt][mb + i];
        }
        if (tid < 32) {
#pragma unroll
            for (int tt = 0; tt < 8; ++tt) ks += kp_s[tt][tid];
        }
        __syncthreads();
    }
#pragma unroll
    for (int i = 0; i < 8; ++i) atomicAdd(&kptv[(b * 64 + n) * 32 + mb + i], acc[i]);
    if (tid < 32) atomicAdd(&ksum[b * 32 + tid], ks);
}

// ---------------------------------------------------------------------------
// epilogue: 128 threads = two independent 16-token tiles; per-sub ksum.
// ---------------------------------------------------------------------------
template <int T>
__global__ __launch_bounds__(128) void epilogue(
    const float* __restrict__ qp, const float* __restrict__ v,
    const float* __restrict__ ksum, const float* __restrict__ kptv,
    const float* __restrict__ proj_w, const float* __restrict__ proj_b,
    const float* __restrict__ ln2_g, const float* __restrict__ ln2_b,
    const float* __restrict__ m1_w, const float* __restrict__ m1_b,
    const float* __restrict__ m2_w, const float* __restrict__ m2_b,
    float* __restrict__ out)
{
    const int sub = threadIdx.x >> 6;
    const int e = threadIdx.x & 63;
    const int tok0 = blockIdx.x * 32 + sub * 16;
    const int b = tok0 / T;

    __shared__ __align__(16) float qp_s[2][16 * 36];
    __shared__ __align__(16) float buf[2][64 * 20];
    __shared__ float ks_s[2][32];
    __shared__ float D_s[2][16];

    for (int idx = e; idx < 512; idx += 64)
        qp_s[sub][(idx >> 5) * 36 + (idx & 31)] = qp[(size_t)tok0 * 32 + idx];
    if (e < 32) ks_s[sub][e] = ksum[b * 32 + e];
    __syncthreads();
    if (e < 16) {
        float D = 1e-8f;
        for (int r = 0; r < 32; ++r) D += qp_s[sub][e * 36 + r] * ks_s[sub][r];
        D_s[sub][e] = D;
    }
    float4 kv4[8];
#pragma unroll
    for (int g = 0; g < 8; ++g)
        kv4[g] = *(const float4*)&kptv[(size_t)(b * 64 + e) * 32 + 4 * g];
    __syncthreads();

    float ya[16];
#pragma unroll
    for (int m = 0; m < 16; ++m) {
        const float4* q4 = (const float4*)&qp_s[sub][m * 36];
        float a = 0.f;
#pragma unroll
        for (int g = 0; g < 8; ++g) {
            const float4 qv = q4[g];
            a += qv.x*kv4[g].x + qv.y*kv4[g].y + qv.z*kv4[g].z + qv.w*kv4[g].w;
        }
        ya[m] = a / D_s[sub][m];
    }
#pragma unroll
    for (int g = 0; g < 4; ++g)
        *(float4*)&buf[sub][e * 20 + 4*g] = make_float4(ya[4*g], ya[4*g+1], ya[4*g+2], ya[4*g+3]);
    __syncthreads();

    float y[16];
    { float acc2[16];
      const float pb = proj_b[e];
#pragma unroll
      for (int m = 0; m < 16; ++m) acc2[m] = pb;
      for (int j = 0; j < 64; ++j) {
          const float w = proj_w[j * 64 + e];
          const float4* a4 = (const float4*)&buf[sub][j * 20];
#pragma unroll
          for (int g = 0; g < 4; ++g) {
              const float4 av = a4[g];
              acc2[4*g+0] += av.x * w; acc2[4*g+1] += av.y * w;
              acc2[4*g+2] += av.z * w; acc2[4*g+3] += av.w * w;
          }
      }
#pragma unroll
      for (int m = 0; m < 16; ++m)
          y[m] = v[(size_t)(tok0 + m) * 64 + e] + acc2[m];
    }
    __syncthreads();

    { const float g2 = ln2_g[e], bb = ln2_b[e];
      float z[16];
#pragma unroll
      for (int m = 0; m < 16; ++m) {
          const float s  = waveReduceSum(y[m]);
          const float s2 = waveReduceSum(y[m] * y[m]);
          const float mu = s * (1.f / 64.f);
          const float var = s2 * (1.f / 64.f) - mu * mu;
          z[m] = (y[m] - mu) * rsqrtf(var + 1e-5f) * g2 + bb;
      }
#pragma unroll
      for (int g = 0; g < 4; ++g)
          *(float4*)&buf[sub][e * 20 + 4*g] = make_float4(z[4*g], z[4*g+1], z[4*g+2], z[4*g+3]);
    }
    __syncthreads();

    float h[16];
    { const float b1 = m1_b[e];
#pragma unroll
      for (int m = 0; m < 16; ++m) h[m] = b1;
      for (int j = 0; j < 64; ++j) {
          const float w = m1_w[j * 64 + e];
          const float4* a4 = (const float4*)&buf[sub][j * 20];
#pragma unroll
          for (int g = 0; g < 4; ++g) {
              const float4 av = a4[g];
              h[4*g+0] += av.x * w; h[4*g+1] += av.y * w;
              h[4*g+2] += av.z * w; h[4*g+3] += av.w * w;
          }
      }
#pragma unroll
      for (int m = 0; m < 16; ++m)
          h[m] = 0.5f * h[m] * (1.f + erff(h[m] * 0.7071067811865476f));
    }
    __syncthreads();
#pragma unroll
    for (int g = 0; g < 4; ++g)
        *(float4*)&buf[sub][e * 20 + 4*g] = make_float4(h[4*g], h[4*g+1], h[4*g+2], h[4*g+3]);
    __syncthreads();

    { const float b2v = m2_b[e];
      float acc4[16];
#pragma unroll
      for (int m = 0; m < 16; ++m) acc4[m] = b2v;
      for (int j = 0; j < 64; ++j) {
          const float w = m2_w[j * 64 + e];
          const float4* a4 = (const float4*)&buf[sub][j * 20];
#pragma unroll
          for (int g = 0; g < 4; ++g) {
              const float4 av = a4[g];
              acc4[4*g+0] += av.x * w; acc4[4*g+1] += av.y * w;
              acc4[4*g+2] += av.z * w; acc4[4*g+3] += av.w * w;
          }
      }
#pragma unroll
      for (int m = 0; m < 16; ++m)
          out[(size_t)(tok0 + m) * 64 + e] = y[m] + acc4[m];
    }
}

// ---------------------------------------------------------------------------
// final_proj v2 (MFMA): 16 tokens, 256 thr = 4 waves.
// ---------------------------------------------------------------------------
__global__ __launch_bounds__(256) void final_proj(
    const float* __restrict__ o2,              // (B*T2,64)
    const unsigned short* __restrict__ wt_hi,  // packed (768,576)
    const unsigned short* __restrict__ wt_lo,
    const float* __restrict__ bias,            // (768)
    float* __restrict__ out)                   // (B*T3,768)
{
    const int tok0 = blockIdx.x * 16;
    const int tid = threadIdx.x;
    const int wv = tid >> 6, l = tid & 63;
    const int l15 = l & 15, lg = l >> 4;

    __shared__ __align__(16) unsigned short Abuf[2 * 16 * KS2];  // 37376B
    unsigned short* A_hi = Abuf;
    unsigned short* A_lo = Abuf + 16 * KS2;

    { const int cl = tid & 15, grp = tid >> 4;
      for (int k = 0; k < 4; ++k) {
#pragma unroll
        for (int ii = 0; ii < 9; ++ii) {
            const int u = grp + ii * 16;       // u = m*9 + r
            const int m = u / 9, r = u % 9;
            const int tok = tok0 + m, bb = tok / T3, tt = tok % T3;
            const int py = tt / 14, px = tt % 14;
            const int iy = py * 2 - 1 + r / 3, ix = px * 2 - 1 + r % 3;
            float val = 0.f;
            if (iy >= 0 && iy < 28 && ix >= 0 && ix < 28)
                val = o2[(size_t)(bb * T2 + iy * 28 + ix) * 64 + k * 16 + cl];
            const int d = k * 144 + cl * 9 + r;
            const unsigned short h = f2bf(val);
            A_hi[m * KS2 + d] = h;
            A_lo[m * KS2 + d] = f2bf(val - __uint_as_float((unsigned int)h << 16));
        }
      }
    }
    __syncthreads();

    f32x4 acc[12];
    { const f32x4 z = {0.f, 0.f, 0.f, 0.f};
#pragma unroll
      for (int nt = 0; nt < 12; ++nt) acc[nt] = z; }

    for (int ks = 0; ks < 18; ++ks) {
        const int ko = ks * 32 + 8 * lg;
        const bf16x8 ah = *(const bf16x8*)&A_hi[l15 * KS2 + ko];
        const bf16x8 al = *(const bf16x8*)&A_lo[l15 * KS2 + ko];
#pragma unroll
        for (int nt = 0; nt < 12; ++nt) {
            const size_t wo = ((size_t)((12 * wv + nt) * 18 + ks) << 9) + (size_t)(l << 3);
            const bf16x8 bh = *(const bf16x8*)&wt_hi[wo];
            const bf16x8 bl = *(const bf16x8*)&wt_lo[wo];
            acc[nt] = __builtin_amdgcn_mfma_f32_16x16x32_bf16(ah, bh, acc[nt], 0, 0, 0);
            acc[nt] = __builtin_amdgcn_mfma_f32_16x16x32_bf16(al, bh, acc[nt], 0, 0, 0);
            acc[nt] = __builtin_amdgcn_mfma_f32_16x16x32_bf16(ah, bl, acc[nt], 0, 0, 0);
        }
    }

#pragma unroll
    for (int nt = 0; nt < 12; ++nt) {
        const int col = 192 * wv + 16 * nt + l15;
        const float bv = bias[col];
#pragma unroll
        for (int r = 0; r < 4; ++r) {
            const int token = 4 * lg + r;
            out[(size_t)(tok0 + token) * 768 + col] = acc[nt][r] + bv;
        }
    }
}

// ---------------------------------------------------------------------------
extern "C" void kernel_launch(void* const* d_in, const int* in_sizes, int n_in,
                              void* d_out, int out_size, void* d_ws, size_t ws_size,
                              hipStream_t stream) {
    const float* x         = (const float*)d_in[0];
    const float* p1_kqv_w  = (const float*)d_in[1];
    const float* p1_kqv_b  = (const float*)d_in[2];
    const float* p1_proj_w = (const float*)d_in[3];
    const float* p1_proj_b = (const float*)d_in[4];
    const float* p1_ln1_g  = (const float*)d_in[5];
    const float* p1_ln1_b  = (const float*)d_in[6];
    const float* p1_ln2_g  = (const float*)d_in[7];
    const float* p1_ln2_b  = (const float*)d_in[8];
    const float* p1_m1_w   = (const float*)d_in[9];
    const float* p1_m1_b   = (const float*)d_in[10];
    const float* p1_m2_w   = (const float*)d_in[11];
    const float* p1_m2_b   = (const float*)d_in[12];
    const float* p1_rf     = (const float*)d_in[13];
    const float* p2_kqv_w  = (const float*)d_in[14];
    const float* p2_kqv_b  = (const float*)d_in[15];
    const float* p2_proj_w = (const float*)d_in[16];
    const float* p2_proj_b = (const float*)d_in[17];
    const float* p2_ln1_g  = (const float*)d_in[18];
    const float* p2_ln1_b  = (const float*)d_in[19];
    const float* p2_ln2_g  = (const float*)d_in[20];
    const float* p2_ln2_b  = (const float*)d_in[21];
    const float* p2_m1_w   = (const float*)d_in[22];
    const float* p2_m1_b   = (const float*)d_in[23];
    const float* p2_m2_w   = (const float*)d_in[24];
    const float* p2_m2_b   = (const float*)d_in[25];
    const float* p2_rf     = (const float*)d_in[26];
    const float* proj_w    = (const float*)d_in[27];
    const float* proj_b    = (const float*)d_in[28];

    float* ws = (float*)d_ws;
    size_t off = 0;
    float* ksum1 = ws + off; off += (size_t)NB * 32;
    float* kptv1 = ws + off; off += (size_t)NB * 64 * 32;
    float* ksum2 = ws + off; off += (size_t)NB * 32;
    float* kptv2 = ws + off; off += (size_t)NB * 64 * 32;
    float* s2v = ws + off; off += 192;      // zeroed region: prep_sums atomics
    float* s3v = ws + off; off += 192;
    float* s2v1 = ws + off; off += 192;
    float* s3v1 = ws + off; off += 192;
    const size_t zero_bytes = off * sizeof(float);
    float* kp1 = ws + off; off += (size_t)NB * T1 * 32;
    float* qp1 = ws + off; off += (size_t)NB * T1 * 32;
    float* v1  = ws + off; off += (size_t)NB * T1 * 64;
    float* o1  = ws + off; off += (size_t)NB * T1 * 64;
    unsigned short* wt1h = (unsigned short*)(ws + off); off += (size_t)192 * KP1 / 2;
    unsigned short* wt1l = (unsigned short*)(ws + off); off += (size_t)192 * KP1 / 2;
    unsigned short* wt2h = (unsigned short*)(ws + off); off += (size_t)192 * 576 / 2;
    unsigned short* wt2l = (unsigned short*)(ws + off); off += (size_t)192 * 576 / 2;
    unsigned short* wtfh = (unsigned short*)(ws + off); off += (size_t)768 * 576 / 2;
    unsigned short* wtfl = (unsigned short*)(ws + off); off += (size_t)768 * 576 / 2;
    unsigned short* rf1h = (unsigned short*)(ws + off); off += 1024;
    unsigned short* rf1l = (unsigned short*)(ws + off); off += 1024;
    unsigned short* rf2h = (unsigned short*)(ws + off); off += 1024;
    unsigned short* rf2l = (unsigned short*)(ws + off); off += 1024;
    size_t off2 = 0;
    float* kp2 = kp1 + off2; off2 += (size_t)NB * T2 * 32;
    float* qp2 = kp1 + off2; off2 += (size_t)NB * T2 * 32;
    float* v2  = kp1 + off2; off2 += (size_t)NB * T2 * 64;
    float* o2  = kp1 + off2; off2 += (size_t)NB * T2 * 64;

    hipMemsetAsync(ws, 0, zero_bytes, stream);

    prep_sums<<<(D2 + 15) / 16, 192, 0, stream>>>(p2_kqv_w, p2_ln1_g, p2_ln1_b, p2_kqv_b, s2v, s3v, D2);
    prep_sums<<<(D1 + 15) / 16, 192, 0, stream>>>(p1_kqv_w, p1_ln1_g, p1_ln1_b, p1_kqv_b, s2v1, s3v1, D1);
    prep_wt<<<(192 * KP1 + 255) / 256, 256, 0, stream>>>(p1_kqv_w, p1_ln1_g, wt1h, wt1l, D1, KP1, 192);
    prep_wt<<<(192 * 576 + 255) / 256, 256, 0, stream>>>(p2_kqv_w, p2_ln1_g, wt2h, wt2l, D2, 576, 192);
    prep_wt<<<(768 * 576 + 255) / 256, 256, 0, stream>>>(proj_w, nullptr, wtfh, wtfl, D2, 576, 768);
    prep_rf<<<8, 256, 0, stream>>>(p1_rf, rf1h, rf1l);
    prep_rf<<<8, 256, 0, stream>>>(p2_rf, rf2h, rf2l);

    front1<<<NB * T1 / 32, 256, 0, stream>>>(x, wt1h, wt1l, s2v1, s3v1, rf1h, rf1l, kp1, qp1, v1);
    reduce_kv<T1, 14><<<NB * 14, 256, 0, stream>>>(kp1, v1, ksum1, kptv1);
    epilogue<T1><<<NB * T1 / 32, 128, 0, stream>>>(qp1, v1, ksum1, kptv1,
                                                   p1_proj_w, p1_proj_b, p1_ln2_g, p1_ln2_b,
                                                   p1_m1_w, p1_m1_b, p1_m2_w, p1_m2_b, o1);
    front2<<<NB * T2 / 16, 128, 0, stream>>>(o1, wt2h, wt2l, s2v, s3v, rf2h, rf2l, kp2, qp2, v2);
    reduce_kv<T2, 7><<<NB * 7, 256, 0, stream>>>(kp2, v2, ksum2, kptv2);
    epilogue<T2><<<NB * T2 / 32, 128, 0, stream>>>(qp2, v2, ksum2, kptv2,
                                                   p2_proj_w, p2_proj_b, p2_ln2_g, p2_ln2_b,
                                                   p2_m1_w, p2_m1_b, p2_m2_w, p2_m2_b, o2);
    final_proj<<<NB * T3 / 16, 256, 0, stream>>>(o2, wtfh, wtfl, proj_b, (float*)d_out);
}

// Round 12
// 754.027 us; speedup vs baseline: 1.3026x; 1.3026x over previous
//
#include <hip/hip_runtime.h>
#include <hip/hip_bf16.h>

#define NB 64
#define T1 3136
#define T2 784
#define T3 196
#define D1 147
#define D2 576

#define KP1 160   // padded K for front1 W^T (147 -> 160)
#define KS1 168   // front1 LDS A row stride (bf16)
#define KS2 584   // front2/final LDS A row stride (bf16)
#define KQ2 72    // kq/epilogue bf16 row stride (144B, 16B-aligned)

typedef __attribute__((ext_vector_type(8))) short bf16x8;
typedef __attribute__((ext_vector_type(4))) float f32x4;

__device__ __forceinline__ unsigned short f2bf(float v) {
    unsigned int u = __float_as_uint(v);
    return (unsigned short)((u + 0x7FFFu + ((u >> 16) & 1u)) >> 16);
}

__device__ __forceinline__ float waveReduceSum(float v) {
#pragma unroll
    for (int off = 32; off > 0; off >>= 1) v += __shfl_down(v, off, 64);
    return __shfl(v, 0, 64);
}

// ---------------------------------------------------------------------------
// prep_sums (parallel, 16-row chunks + atomics into pre-zeroed s2/s3).
// prep_wt: split-bf16 W^T in PACKED tile layout (1KB per (16-col tile, 32-K)).
// prep_rf: same packing for rf (N=32, K=64).
// ---------------------------------------------------------------------------
__global__ __launch_bounds__(192) void prep_sums(
    const float* __restrict__ w, const float* __restrict__ g,
    const float* __restrict__ bb, const float* __restrict__ kqvb,
    float* __restrict__ s2, float* __restrict__ s3, int D)
{
    const int col = threadIdx.x;
    const int d0 = blockIdx.x * 16;
    const int d1 = (d0 + 16 < D) ? d0 + 16 : D;
    float a2 = 0.f, a3 = 0.f;
    for (int d = d0; d < d1; ++d) {
        const float wv = w[d * 192 + col];
        a2 += wv * g[d];
        a3 += wv * bb[d];
    }
    if (blockIdx.x == 0) a3 += kqvb[col];
    atomicAdd(&s2[col], a2);
    atomicAdd(&s3[col], a3);
}

__global__ __launch_bounds__(256) void prep_wt(
    const float* __restrict__ w, const float* __restrict__ g,
    unsigned short* __restrict__ hi, unsigned short* __restrict__ lo,
    int D, int K, int N)
{
    const int i = blockIdx.x * 256 + threadIdx.x;
    if (i >= N * K) return;
    const int n = i / K, k = i % K;
    const float v = (k < D) ? w[k * N + n] * (g ? g[k] : 1.f) : 0.f;
    const unsigned short h = f2bf(v);
    const float hf = __uint_as_float((unsigned int)h << 16);
    const size_t pidx = (size_t)((n >> 4) * (K >> 5) + (k >> 5)) * 512
                      + (size_t)((((k >> 3) & 3) * 16 + (n & 15)) * 8 + (k & 7));
    hi[pidx] = h;
    lo[pidx] = f2bf(v - hf);
}

__global__ __launch_bounds__(256) void prep_rf(
    const float* __restrict__ rf,              // (32,64) row n, col k
    unsigned short* __restrict__ hi, unsigned short* __restrict__ lo)
{
    const int i = blockIdx.x * 256 + threadIdx.x;
    if (i >= 2048) return;
    const int n = i >> 6, k = i & 63;
    const float v = rf[i];
    const unsigned short h = f2bf(v);
    const float hf = __uint_as_float((unsigned int)h << 16);
    const int pidx = ((n >> 4) * 2 + (k >> 5)) * 512
                   + ((((k >> 3) & 3) * 16 + (n & 15)) * 8 + (k & 7));
    hi[pidx] = h;
    lo[pidx] = f2bf(v - hf);
}

// ---------------------------------------------------------------------------
// front1 v8 (full MFMA): 32 tokens, 256 thr = 4 waves.
// ---------------------------------------------------------------------------
__global__ __launch_bounds__(256) void front1(
    const float* __restrict__ x,
    const unsigned short* __restrict__ wt_hi,  // packed (192,KP1)
    const unsigned short* __restrict__ wt_lo,
    const float* __restrict__ s2v, const float* __restrict__ s3v,
    const unsigned short* __restrict__ rf_hi,  // packed (32,64)
    const unsigned short* __restrict__ rf_lo,
    float* __restrict__ kp, float* __restrict__ qp,
    float* __restrict__ v_out)
{
    const int tok0 = blockIdx.x * 32;
    const int b = tok0 / T1;
    const int tbase = tok0 % T1;
    const int tid = threadIdx.x;
    const int wv = tid >> 6, l = tid & 63;
    const int l15 = l & 15, lg = l >> 4;

    __shared__ __align__(16) unsigned short Abuf[2 * 32 * KS1];  // 21504B
    __shared__ float ps_sum[256], ps_sq[256];
    __shared__ float mu_s[32], rs_s[32], xd_s[64];

    unsigned short* A_hi = Abuf;
    unsigned short* A_lo = Abuf + 32 * KS1;
    unsigned short* kqh = Abuf;                // [64][KQ2], aliases post-barrier B
    unsigned short* kql = Abuf + 64 * KQ2;

    // --- fill: m = tid>>3 (token), j = tid&7 (d-slice) ---
    { const int m = tid >> 3, j = tid & 7;
      const int t = tbase + m;
      const int py = t / 56, px = t % 56;
      const int iy0 = py * 4 - 2, ix0 = px * 4 - 2;
      float sm = 0.f, sq = 0.f;
      for (int d = j; d < KS1; d += 8) {
          float val = 0.f;
          if (d < D1) {
              const int cc = d / 49, r = d % 49, ki = r / 7, kj = r % 7;
              const int iy = iy0 + ki, ix = ix0 + kj;
              if (iy >= 0 && iy < 224 && ix >= 0 && ix < 224)
                  val = x[((b * 3 + cc) * 224 + iy) * 224 + ix];
          }
          sm += val; sq += val * val;
          const unsigned short h = f2bf(val);
          A_hi[m * KS1 + d] = h;
          A_lo[m * KS1 + d] = f2bf(val - __uint_as_float((unsigned int)h << 16));
      }
      ps_sum[tid] = sm; ps_sq[tid] = sq; }
    __syncthreads();                           // barrier A
    if (tid < 32) {
        float s = 0.f, s2 = 0.f;
#pragma unroll
        for (int j2 = 0; j2 < 8; ++j2) { s += ps_sum[tid*8+j2]; s2 += ps_sq[tid*8+j2]; }
        const float mu = s * (1.f / D1);
        mu_s[tid] = mu; rs_s[tid] = rsqrtf(s2 * (1.f / D1) - mu * mu + 1e-5f);
    }

    // --- MFMA matvec: wave wv owns N-tiles {3wv..3wv+2} x M-tiles {0,1} ---
    f32x4 acc[2][3];
    { const f32x4 z = {0.f, 0.f, 0.f, 0.f};
#pragma unroll
      for (int mt = 0; mt < 2; ++mt)
#pragma unroll
        for (int nt = 0; nt < 3; ++nt) acc[mt][nt] = z; }

    for (int ks = 0; ks < 5; ++ks) {
        const int ko = ks * 32 + 8 * lg;
        const bf16x8 ah0 = *(const bf16x8*)&A_hi[l15 * KS1 + ko];
        const bf16x8 ah1 = *(const bf16x8*)&A_hi[(16 + l15) * KS1 + ko];
        const bf16x8 al0 = *(const bf16x8*)&A_lo[l15 * KS1 + ko];
        const bf16x8 al1 = *(const bf16x8*)&A_lo[(16 + l15) * KS1 + ko];
#pragma unroll
        for (int nt = 0; nt < 3; ++nt) {
            const size_t wo = ((size_t)((3 * wv + nt) * 5 + ks) << 9) + (size_t)(l << 3);
            const bf16x8 bh = *(const bf16x8*)&wt_hi[wo];
            const bf16x8 bl = *(const bf16x8*)&wt_lo[wo];
            acc[0][nt] = __builtin_amdgcn_mfma_f32_16x16x32_bf16(ah0, bh, acc[0][nt], 0, 0, 0);
            acc[1][nt] = __builtin_amdgcn_mfma_f32_16x16x32_bf16(ah1, bh, acc[1][nt], 0, 0, 0);
            acc[0][nt] = __builtin_amdgcn_mfma_f32_16x16x32_bf16(al0, bh, acc[0][nt], 0, 0, 0);
            acc[1][nt] = __builtin_amdgcn_mfma_f32_16x16x32_bf16(al1, bh, acc[1][nt], 0, 0, 0);
            acc[0][nt] = __builtin_amdgcn_mfma_f32_16x16x32_bf16(ah0, bl, acc[0][nt], 0, 0, 0);
            acc[1][nt] = __builtin_amdgcn_mfma_f32_16x16x32_bf16(ah1, bl, acc[1][nt], 0, 0, 0);
        }
    }
    __syncthreads();                           // barrier B: Abuf dead, mu_s ready

    // --- fold-correction + scatter (kq -> bf16 split LDS, v -> global) ---
    float xk[2][4], xq[2][4];
#pragma unroll
    for (int mt = 0; mt < 2; ++mt)
#pragma unroll
        for (int r = 0; r < 4; ++r) { xk[mt][r] = 0.f; xq[mt][r] = 0.f; }

#pragma unroll
    for (int nt = 0; nt < 3; ++nt) {
        const int col = 48 * wv + 16 * nt + l15;
        const int third = col >> 6, cc = col & 63;
        const float s2c = s2v[col], s3c = s3v[col];
#pragma unroll
        for (int mt = 0; mt < 2; ++mt) {
#pragma unroll
            for (int r = 0; r < 4; ++r) {
                const int token = mt * 16 + 4 * lg + r;
                const float o = rs_s[token] * (acc[mt][nt][r] - mu_s[token] * s2c) + s3c;
                if (third == 2) {
                    v_out[(size_t)(tok0 + token) * 64 + cc] = o;
                } else {
                    const int row = third * 32 + token;
                    const unsigned short h = f2bf(o);
                    kqh[row * KQ2 + cc] = h;
                    kql[row * KQ2 + cc] = f2bf(o - __uint_as_float((unsigned int)h << 16));
                    if (third == 0) xk[mt][r] += o * o; else xq[mt][r] += o * o;
                }
            }
        }
    }
#pragma unroll
    for (int mt = 0; mt < 2; ++mt) {
#pragma unroll
        for (int r = 0; r < 4; ++r) {
            float a = xk[mt][r], q2 = xq[mt][r];
#pragma unroll
            for (int off = 1; off < 16; off <<= 1) {
                a  += __shfl_xor(a,  off, 64);
                q2 += __shfl_xor(q2, off, 64);
            }
            if (l15 == 0) {
                const int token = mt * 16 + 4 * lg + r;
                ps_sum[wv * 64 + token]      = a;
                ps_sum[wv * 64 + 32 + token] = q2;
            }
        }
    }
    __syncthreads();                           // barrier C
    if (tid < 64)
        xd_s[tid] = 0.5f * (ps_sum[tid] + ps_sum[64+tid] + ps_sum[128+tid] + ps_sum[192+tid]);
    __syncthreads();                           // barrier D

    // --- prm_exp via MFMA: A = kq[64][64], B = rf[32][64]; wave wv = M-tile ---
    f32x4 pacc[2];
    { const f32x4 z = {0.f, 0.f, 0.f, 0.f}; pacc[0] = z; pacc[1] = z; }
#pragma unroll
    for (int ks = 0; ks < 2; ++ks) {
        const int ko = ks * 32 + 8 * lg;
        const bf16x8 ah = *(const bf16x8*)&kqh[(16 * wv + l15) * KQ2 + ko];
        const bf16x8 al = *(const bf16x8*)&kql[(16 * wv + l15) * KQ2 + ko];
#pragma unroll
        for (int nt = 0; nt < 2; ++nt) {
            const int wo = (nt * 2 + ks) * 512 + l * 8;
            const bf16x8 bh = *(const bf16x8*)&rf_hi[wo];
            const bf16x8 bl = *(const bf16x8*)&rf_lo[wo];
            pacc[nt] = __builtin_amdgcn_mfma_f32_16x16x32_bf16(ah, bh, pacc[nt], 0, 0, 0);
            pacc[nt] = __builtin_amdgcn_mfma_f32_16x16x32_bf16(al, bh, pacc[nt], 0, 0, 0);
            pacc[nt] = __builtin_amdgcn_mfma_f32_16x16x32_bf16(ah, bl, pacc[nt], 0, 0, 0);
        }
    }
#pragma unroll
    for (int nt = 0; nt < 2; ++nt) {
#pragma unroll
        for (int r = 0; r < 4; ++r) {
            const int row = 16 * wv + 4 * lg + r;
            const int half = row >> 5, token = row & 31;
            const float p = expf(pacc[nt][r] - xd_s[row]) * 0.1767766952966369f;
            (half ? qp : kp)[(size_t)(tok0 + token) * 32 + nt * 16 + l15] = p;
        }
    }
}

// ---------------------------------------------------------------------------
// front2 v6 (full MFMA): 16 tokens, 128 thr = 2 waves.
// ---------------------------------------------------------------------------
__global__ __launch_bounds__(128) void front2(
    const float* __restrict__ src,             // o1 (B*T1,64)
    const unsigned short* __restrict__ wt_hi,  // packed (192,576)
    const unsigned short* __restrict__ wt_lo,
    const float* __restrict__ s2v, const float* __restrict__ s3v,
    const unsigned short* __restrict__ rf_hi,
    const unsigned short* __restrict__ rf_lo,
    float* __restrict__ kp, float* __restrict__ qp,
    float* __restrict__ v_out)
{
    const int tok0 = blockIdx.x * 16;
    const int b = tok0 / T2;
    const int tbase = tok0 % T2;
    const int tid = threadIdx.x;
    const int wv = tid >> 6, l = tid & 63;
    const int l15 = l & 15, lg = l >> 4;

    __shared__ __align__(16) unsigned short Abuf[2 * 16 * KS2];  // 37376B
    __shared__ float ps_sum[128], ps_sq[128];
    __shared__ float mu_s[16], rs_s[16], xd_s[32];

    unsigned short* A_hi = Abuf;
    unsigned short* A_lo = Abuf + 16 * KS2;
    unsigned short* kqh = Abuf;                // [32][KQ2]
    unsigned short* kql = Abuf + 32 * KQ2;

    { const int g16 = tid >> 3, ch = tid & 7;
      const int tmine = tbase + g16;
      const int py = tmine / 28, px = tmine % 28;
      const int iy0 = py * 2 - 1, ix0 = px * 2 - 1;
      const float* srcb = src + (size_t)b * T1 * 64 + ch;
      unsigned short* Ah = &A_hi[g16 * KS2];
      unsigned short* Al = &A_lo[g16 * KS2];
      float sm = 0.f, sq = 0.f;
#pragma unroll
      for (int r = 0; r < 9; ++r) {
          const int iy = iy0 + r / 3, ix = ix0 + r % 3;
          const bool ok = (iy >= 0 && iy < 56 && ix >= 0 && ix < 56);
          const float* sp = srcb + (size_t)(iy * 56 + ix) * 64;
#pragma unroll
          for (int c = 0; c < 8; ++c) {
              const float val = ok ? sp[c * 8] : 0.f;
              sm += val; sq += val * val;
              const int d = (c * 8 + ch) * 9 + r;
              const unsigned short h = f2bf(val);
              Ah[d] = h;
              Al[d] = f2bf(val - __uint_as_float((unsigned int)h << 16));
          }
      }
      ps_sum[tid] = sm; ps_sq[tid] = sq; }
    __syncthreads();                           // barrier A
    if (tid < 16) {
        float s = 0.f, s2 = 0.f;
#pragma unroll
        for (int j = 0; j < 8; ++j) { s += ps_sum[tid*8+j]; s2 += ps_sq[tid*8+j]; }
        const float mu = s * (1.f / D2);
        mu_s[tid] = mu; rs_s[tid] = rsqrtf(s2 * (1.f / D2) - mu * mu + 1e-5f);
    }

    f32x4 acc[6];
    { const f32x4 z = {0.f, 0.f, 0.f, 0.f};
#pragma unroll
      for (int nt = 0; nt < 6; ++nt) acc[nt] = z; }

    for (int ks = 0; ks < 18; ++ks) {
        const int ko = ks * 32 + 8 * lg;
        const bf16x8 ah = *(const bf16x8*)&A_hi[l15 * KS2 + ko];
        const bf16x8 al = *(const bf16x8*)&A_lo[l15 * KS2 + ko];
#pragma unroll
        for (int nt = 0; nt < 6; ++nt) {
            const size_t wo = ((size_t)((6 * wv + nt) * 18 + ks) << 9) + (size_t)(l << 3);
            const bf16x8 bh = *(const bf16x8*)&wt_hi[wo];
            const bf16x8 bl = *(const bf16x8*)&wt_lo[wo];
            acc[nt] = __builtin_amdgcn_mfma_f32_16x16x32_bf16(ah, bh, acc[nt], 0, 0, 0);
            acc[nt] = __builtin_amdgcn_mfma_f32_16x16x32_bf16(al, bh, acc[nt], 0, 0, 0);
            acc[nt] = __builtin_amdgcn_mfma_f32_16x16x32_bf16(ah, bl, acc[nt], 0, 0, 0);
        }
    }
    __syncthreads();                           // barrier B

    float xk[4], xq[4];
#pragma unroll
    for (int r = 0; r < 4; ++r) { xk[r] = 0.f; xq[r] = 0.f; }

#pragma unroll
    for (int nt = 0; nt < 6; ++nt) {
        const int col = 96 * wv + 16 * nt + l15;
        const int third = col >> 6, cc = col & 63;
        const float s2c = s2v[col], s3c = s3v[col];
#pragma unroll
        for (int r = 0; r < 4; ++r) {
            const int token = 4 * lg + r;
            const float o = rs_s[token] * (acc[nt][r] - mu_s[token] * s2c) + s3c;
            if (third == 2) {
                v_out[(size_t)(tok0 + token) * 64 + cc] = o;
            } else {
                const int row = third * 16 + token;
                const unsigned short h = f2bf(o);
                kqh[row * KQ2 + cc] = h;
                kql[row * KQ2 + cc] = f2bf(o - __uint_as_float((unsigned int)h << 16));
                if (third == 0) xk[r] += o * o; else xq[r] += o * o;
            }
        }
    }
#pragma unroll
    for (int r = 0; r < 4; ++r) {
        float a = xk[r], q2 = xq[r];
#pragma unroll
        for (int off = 1; off < 16; off <<= 1) {
            a  += __shfl_xor(a,  off, 64);
            q2 += __shfl_xor(q2, off, 64);
        }
        if (l15 == 0) {
            const int token = 4 * lg + r;
            ps_sum[wv * 32 + token]      = a;
            ps_sum[wv * 32 + 16 + token] = q2;
        }
    }
    __syncthreads();                           // barrier C
    if (tid < 32)
        xd_s[tid] = 0.5f * (ps_sum[tid] + ps_sum[32 + tid]);
    __syncthreads();                           // barrier D

    f32x4 pacc[2];
    { const f32x4 z = {0.f, 0.f, 0.f, 0.f}; pacc[0] = z; pacc[1] = z; }
#pragma unroll
    for (int ks = 0; ks < 2; ++ks) {
        const int ko = ks * 32 + 8 * lg;
        const bf16x8 ah = *(const bf16x8*)&kqh[(16 * wv + l15) * KQ2 + ko];
        const bf16x8 al = *(const bf16x8*)&kql[(16 * wv + l15) * KQ2 + ko];
#pragma unroll
        for (int nt = 0; nt < 2; ++nt) {
            const int wo = (nt * 2 + ks) * 512 + l * 8;
            const bf16x8 bh = *(const bf16x8*)&rf_hi[wo];
            const bf16x8 bl = *(const bf16x8*)&rf_lo[wo];
            pacc[nt] = __builtin_amdgcn_mfma_f32_16x16x32_bf16(ah, bh, pacc[nt], 0, 0, 0);
            pacc[nt] = __builtin_amdgcn_mfma_f32_16x16x32_bf16(al, bh, pacc[nt], 0, 0, 0);
            pacc[nt] = __builtin_amdgcn_mfma_f32_16x16x32_bf16(ah, bl, pacc[nt], 0, 0, 0);
        }
    }
#pragma unroll
    for (int nt = 0; nt < 2; ++nt) {
#pragma unroll
        for (int r = 0; r < 4; ++r) {
            const int row = 16 * wv + 4 * lg + r;
            const int half = row >> 4, token = row & 15;
            const float p = expf(pacc[nt][r] - xd_s[row]) * 0.1767766952966369f;
            (half ? qp : kp)[(size_t)(tok0 + token) * 32 + nt * 16 + l15] = p;
        }
    }
}

// ---------------------------------------------------------------------------
// reduce_kv, split S-ways over T with atomics (ksum/kptv pre-zeroed)
// ---------------------------------------------------------------------------
template <int T, int S>
__global__ __launch_bounds__(256) void reduce_kv(
    const float* __restrict__ kp, const float* __restrict__ v,
    float* __restrict__ ksum, float* __restrict__ kptv)
{
    const int b = blockIdx.x / S, s = blockIdx.x % S;
    const int chunk = T / S;
    const int tid = threadIdx.x;
    __shared__ float kp_s[8][32];
    __shared__ float v_s[8][64];
    float acc[8] = {0.f, 0.f, 0.f, 0.f, 0.f, 0.f, 0.f, 0.f};
    float ks = 0.f;
    const int n = tid >> 2;
    const int mb = (tid & 3) * 8;
    const float* kpb = kp + (size_t)b * T * 32;
    const float* vb  = v  + (size_t)b * T * 64;

    for (int t0 = s * chunk; t0 < (s + 1) * chunk; t0 += 8) {
        kp_s[tid >> 5][tid & 31] = kpb[(t0 + (tid >> 5)) * 32 + (tid & 31)];
        {
            const int i0 = tid * 2, i1 = tid * 2 + 1;
            v_s[i0 >> 6][i0 & 63] = vb[(t0 + (i0 >> 6)) * 64 + (i0 & 63)];
            v_s[i1 >> 6][i1 & 63] = vb[(t0 + (i1 >> 6)) * 64 + (i1 & 63)];
        }
        __syncthreads();
#pragma unroll
        for (int tt = 0; tt < 8; ++tt) {
            const float vv = v_s[tt][n];
#pragma unroll
            for (int i = 0; i < 8; ++i) acc[i] += vv * kp_s[tt][mb + i];
        }
        if (tid < 32) {
#pragma unroll
            for (int tt = 0; tt < 8; ++tt) ks += kp_s[tt][tid];
        }
        __syncthreads();
    }
#pragma unroll
    for (int i = 0; i < 8; ++i) atomicAdd(&kptv[(b * 64 + n) * 32 + mb + i], acc[i]);
    if (tid < 32) atomicAdd(&ksum[b * 32 + tid], ks);
}

// ---------------------------------------------------------------------------
// epilogue v2 (MFMA): 128 threads = 2 waves, each wave owns one 16-token tile.
// ya (fp32, cheap) -> bf16-split wave-private LDS A -> MFMA proj (+b, +v;
// y kept in C frags) -> in-register LN (4-nt sum + 16-lane shfl_xor) ->
// z -> LDS -> MFMA m1 (+b, GELU) -> LDS -> MFMA m2 (+b, +y) -> store.
// Weight mats (64x64) pre-packed split-bf16. Replaces ~3072 fp32 MACs +
// ~770 LDS b128 reads per thread with 72 MFMA/wave.
// ---------------------------------------------------------------------------
template <int T>
__global__ __launch_bounds__(128) void epilogue(
    const float* __restrict__ qp, const float* __restrict__ v,
    const float* __restrict__ ksum, const float* __restrict__ kptv,
    const unsigned short* __restrict__ pw_hi, const unsigned short* __restrict__ pw_lo,
    const float* __restrict__ proj_b,
    const float* __restrict__ ln2_g, const float* __restrict__ ln2_b,
    const unsigned short* __restrict__ m1_hi, const unsigned short* __restrict__ m1_lo,
    const float* __restrict__ m1_b,
    const unsigned short* __restrict__ m2_hi, const unsigned short* __restrict__ m2_lo,
    const float* __restrict__ m2_b,
    float* __restrict__ out)
{
    const int sub = threadIdx.x >> 6;
    const int l = threadIdx.x & 63;
    const int l15 = l & 15, lg = l >> 4;
    const int tok0 = blockIdx.x * 32 + sub * 16;
    const int b = tok0 / T;

    __shared__ __align__(16) float qp_s[2][16 * 36];
    __shared__ __align__(16) unsigned short Ah[2][16 * KQ2];
    __shared__ __align__(16) unsigned short Al[2][16 * KQ2];
    __shared__ float ks_s[2][32];
    __shared__ float D_s[2][16];

    for (int idx = l; idx < 512; idx += 64)
        qp_s[sub][(idx >> 5) * 36 + (idx & 31)] = qp[(size_t)tok0 * 32 + idx];
    if (l < 32) ks_s[sub][l] = ksum[b * 32 + l];
    __syncthreads();
    if (l < 16) {
        float D = 1e-8f;
        for (int r = 0; r < 32; ++r) D += qp_s[sub][l * 36 + r] * ks_s[sub][r];
        D_s[sub][l] = D;
    }
    float4 kv4[8];
#pragma unroll
    for (int g = 0; g < 8; ++g)
        kv4[g] = *(const float4*)&kptv[(size_t)(b * 64 + l) * 32 + 4 * g];
    __syncthreads();

    // ya (col l across 16 tokens) -> bf16 split into A[token][l]
    unsigned short* ah = Ah[sub];
    unsigned short* al = Al[sub];
#pragma unroll
    for (int m = 0; m < 16; ++m) {
        const float4* q4 = (const float4*)&qp_s[sub][m * 36];
        float a = 0.f;
#pragma unroll
        for (int g = 0; g < 8; ++g) {
            const float4 qv = q4[g];
            a += qv.x*kv4[g].x + qv.y*kv4[g].y + qv.z*kv4[g].z + qv.w*kv4[g].w;
        }
        a /= D_s[sub][m];
        const unsigned short h = f2bf(a);
        ah[m * KQ2 + l] = h;
        al[m * KQ2 + l] = f2bf(a - __uint_as_float((unsigned int)h << 16));
    }
    __syncthreads();

    // MFMA proj -> y (C frags: token = 4lg+r, col = 16nt+l15)
    f32x4 y[4];
    { const f32x4 z = {0.f, 0.f, 0.f, 0.f};
#pragma unroll
      for (int nt = 0; nt < 4; ++nt) y[nt] = z; }
#pragma unroll
    for (int ks = 0; ks < 2; ++ks) {
        const int ko = ks * 32 + 8 * lg;
        const bf16x8 fa = *(const bf16x8*)&ah[l15 * KQ2 + ko];
        const bf16x8 fl = *(const bf16x8*)&al[l15 * KQ2 + ko];
#pragma unroll
        for (int nt = 0; nt < 4; ++nt) {
            const int wo = (nt * 2 + ks) * 512 + l * 8;
            const bf16x8 bh = *(const bf16x8*)&pw_hi[wo];
            const bf16x8 bl = *(const bf16x8*)&pw_lo[wo];
            y[nt] = __builtin_amdgcn_mfma_f32_16x16x32_bf16(fa, bh, y[nt], 0, 0, 0);
            y[nt] = __builtin_amdgcn_mfma_f32_16x16x32_bf16(fl, bh, y[nt], 0, 0, 0);
            y[nt] = __builtin_amdgcn_mfma_f32_16x16x32_bf16(fa, bl, y[nt], 0, 0, 0);
        }
    }
    // y += proj_b + v
#pragma unroll
    for (int nt = 0; nt < 4; ++nt) {
        const int col = 16 * nt + l15;
        const float pb = proj_b[col];
#pragma unroll
        for (int r = 0; r < 4; ++r)
            y[nt][r] += pb + v[(size_t)(tok0 + 4 * lg + r) * 64 + col];
    }
    __syncthreads();                           // Ah/Al free

    // in-register LN over 64 cols per token; z -> LDS (bf16 split)
    { float g2c[4], b2c[4];
#pragma unroll
      for (int nt = 0; nt < 4; ++nt) { g2c[nt] = ln2_g[16*nt+l15]; b2c[nt] = ln2_b[16*nt+l15]; }
#pragma unroll
      for (int r = 0; r < 4; ++r) {
          float s = y[0][r] + y[1][r] + y[2][r] + y[3][r];
          float s2 = y[0][r]*y[0][r] + y[1][r]*y[1][r] + y[2][r]*y[2][r] + y[3][r]*y[3][r];
#pragma unroll
          for (int off = 1; off < 16; off <<= 1) {
              s  += __shfl_xor(s,  off, 64);
              s2 += __shfl_xor(s2, off, 64);
          }
          const float mu = s * (1.f / 64.f);
          const float rs = rsqrtf(s2 * (1.f / 64.f) - mu * mu + 1e-5f);
          const int row = (4 * lg + r) * KQ2;
#pragma unroll
          for (int nt = 0; nt < 4; ++nt) {
              const float z = (y[nt][r] - mu) * rs * g2c[nt] + b2c[nt];
              const unsigned short h = f2bf(z);
              ah[row + 16 * nt + l15] = h;
              al[row + 16 * nt + l15] = f2bf(z - __uint_as_float((unsigned int)h << 16));
          }
      } }
    __syncthreads();

    // MFMA m1 -> h, GELU, -> LDS
    f32x4 hf[4];
    { const f32x4 z = {0.f, 0.f, 0.f, 0.f};
#pragma unroll
      for (int nt = 0; nt < 4; ++nt) hf[nt] = z; }
#pragma unroll
    for (int ks = 0; ks < 2; ++ks) {
        const int ko = ks * 32 + 8 * lg;
        const bf16x8 fa = *(const bf16x8*)&ah[l15 * KQ2 + ko];
        const bf16x8 fl = *(const bf16x8*)&al[l15 * KQ2 + ko];
#pragma unroll
        for (int nt = 0; nt < 4; ++nt) {
            const int wo = (nt * 2 + ks) * 512 + l * 8;
            const bf16x8 bh = *(const bf16x8*)&m1_hi[wo];
            const bf16x8 bl = *(const bf16x8*)&m1_lo[wo];
            hf[nt] = __builtin_amdgcn_mfma_f32_16x16x32_bf16(fa, bh, hf[nt], 0, 0, 0);
            hf[nt] = __builtin_amdgcn_mfma_f32_16x16x32_bf16(fl, bh, hf[nt], 0, 0, 0);
            hf[nt] = __builtin_amdgcn_mfma_f32_16x16x32_bf16(fa, bl, hf[nt], 0, 0, 0);
        }
    }
    __syncthreads();                           // Ah/Al free again
#pragma unroll
    for (int nt = 0; nt < 4; ++nt) {
        const float b1 = m1_b[16 * nt + l15];
#pragma unroll
        for (int r = 0; r < 4; ++r) {
            const float t = hf[nt][r] + b1;
            const float gl = 0.5f * t * (1.f + erff(t * 0.7071067811865476f));
            const unsigned short h = f2bf(gl);
            const int idx = (4 * lg + r) * KQ2 + 16 * nt + l15;
            ah[idx] = h;
            al[idx] = f2bf(gl - __uint_as_float((unsigned int)h << 16));
        }
    }
    __syncthreads();

    // MFMA m2 -> out = y + m2(h) + m2_b
    f32x4 oacc[4];
    { const f32x4 z = {0.f, 0.f, 0.f, 0.f};
#pragma unroll
      for (int nt = 0; nt < 4; ++nt) oacc[nt] = z; }
#pragma unroll
    for (int ks = 0; ks < 2; ++ks) {
        const int ko = ks * 32 + 8 * lg;
        const bf16x8 fa = *(const bf16x8*)&ah[l15 * KQ2 + ko];
        const bf16x8 fl = *(const bf16x8*)&al[l15 * KQ2 + ko];
#pragma unroll
        for (int nt = 0; nt < 4; ++nt) {
            const int wo = (nt * 2 + ks) * 512 + l * 8;
            const bf16x8 bh = *(const bf16x8*)&m2_hi[wo];
            const bf16x8 bl = *(const bf16x8*)&m2_lo[wo];
            oacc[nt] = __builtin_amdgcn_mfma_f32_16x16x32_bf16(fa, bh, oacc[nt], 0, 0, 0);
            oacc[nt] = __builtin_amdgcn_mfma_f32_16x16x32_bf16(fl, bh, oacc[nt], 0, 0, 0);
            oacc[nt] = __builtin_amdgcn_mfma_f32_16x16x32_bf16(fa, bl, oacc[nt], 0, 0, 0);
        }
    }
#pragma unroll
    for (int nt = 0; nt < 4; ++nt) {
        const int col = 16 * nt + l15;
        const float b2v = m2_b[col];
#pragma unroll
        for (int r = 0; r < 4; ++r)
            out[(size_t)(tok0 + 4 * lg + r) * 64 + col] = y[nt][r] + oacc[nt][r] + b2v;
    }
}

// ---------------------------------------------------------------------------
// final_proj v2 (MFMA): 16 tokens, 256 thr = 4 waves.
// ---------------------------------------------------------------------------
__global__ __launch_bounds__(256) void final_proj(
    const float* __restrict__ o2,              // (B*T2,64)
    const unsigned short* __restrict__ wt_hi,  // packed (768,576)
    const unsigned short* __restrict__ wt_lo,
    const float* __restrict__ bias,            // (768)
    float* __restrict__ out)                   // (B*T3,768)
{
    const int tok0 = blockIdx.x * 16;
    const int tid = threadIdx.x;
    const int wv = tid >> 6, l = tid & 63;
    const int l15 = l & 15, lg = l >> 4;

    __shared__ __align__(16) unsigned short Abuf[2 * 16 * KS2];  // 37376B
    unsigned short* A_hi = Abuf;
    unsigned short* A_lo = Abuf + 16 * KS2;

    { const int cl = tid & 15, grp = tid >> 4;
      for (int k = 0; k < 4; ++k) {
#pragma unroll
        for (int ii = 0; ii < 9; ++ii) {
            const int u = grp + ii * 16;       // u = m*9 + r
            const int m = u / 9, r = u % 9;
            const int tok = tok0 + m, bb = tok / T3, tt = tok % T3;
            const int py = tt / 14, px = tt % 14;
            const int iy = py * 2 - 1 + r / 3, ix = px * 2 - 1 + r % 3;
            float val = 0.f;
            if (iy >= 0 && iy < 28 && ix >= 0 && ix < 28)
                val = o2[(size_t)(bb * T2 + iy * 28 + ix) * 64 + k * 16 + cl];
            const int d = k * 144 + cl * 9 + r;
            const unsigned short h = f2bf(val);
            A_hi[m * KS2 + d] = h;
            A_lo[m * KS2 + d] = f2bf(val - __uint_as_float((unsigned int)h << 16));
        }
      }
    }
    __syncthreads();

    f32x4 acc[12];
    { const f32x4 z = {0.f, 0.f, 0.f, 0.f};
#pragma unroll
      for (int nt = 0; nt < 12; ++nt) acc[nt] = z; }

    for (int ks = 0; ks < 18; ++ks) {
        const int ko = ks * 32 + 8 * lg;
        const bf16x8 ah = *(const bf16x8*)&A_hi[l15 * KS2 + ko];
        const bf16x8 al = *(const bf16x8*)&A_lo[l15 * KS2 + ko];
#pragma unroll
        for (int nt = 0; nt < 12; ++nt) {
            const size_t wo = ((size_t)((12 * wv + nt) * 18 + ks) << 9) + (size_t)(l << 3);
            const bf16x8 bh = *(const bf16x8*)&wt_hi[wo];
            const bf16x8 bl = *(const bf16x8*)&wt_lo[wo];
            acc[nt] = __builtin_amdgcn_mfma_f32_16x16x32_bf16(ah, bh, acc[nt], 0, 0, 0);
            acc[nt] = __builtin_amdgcn_mfma_f32_16x16x32_bf16(al, bh, acc[nt], 0, 0, 0);
            acc[nt] = __builtin_amdgcn_mfma_f32_16x16x32_bf16(ah, bl, acc[nt], 0, 0, 0);
        }
    }

#pragma unroll
    for (int nt = 0; nt < 12; ++nt) {
        const int col = 192 * wv + 16 * nt + l15;
        const float bv = bias[col];
#pragma unroll
        for (int r = 0; r < 4; ++r) {
            const int token = 4 * lg + r;
            out[(size_t)(tok0 + token) * 768 + col] = acc[nt][r] + bv;
        }
    }
}

// ---------------------------------------------------------------------------
extern "C" void kernel_launch(void* const* d_in, const int* in_sizes, int n_in,
                              void* d_out, int out_size, void* d_ws, size_t ws_size,
                              hipStream_t stream) {
    const float* x         = (const float*)d_in[0];
    const float* p1_kqv_w  = (const float*)d_in[1];
    const float* p1_kqv_b  = (const float*)d_in[2];
    const float* p1_proj_w = (const float*)d_in[3];
    const float* p1_proj_b = (const float*)d_in[4];
    const float* p1_ln1_g  = (const float*)d_in[5];
    const float* p1_ln1_b  = (const float*)d_in[6];
    const float* p1_ln2_g  = (const float*)d_in[7];
    const float* p1_ln2_b  = (const float*)d_in[8];
    const float* p1_m1_w   = (const float*)d_in[9];
    const float* p1_m1_b   = (const float*)d_in[10];
    const float* p1_m2_w   = (const float*)d_in[11];
    const float* p1_m2_b   = (const float*)d_in[12];
    const float* p1_rf     = (const float*)d_in[13];
    const float* p2_kqv_w  = (const float*)d_in[14];
    const float* p2_kqv_b  = (const float*)d_in[15];
    const float* p2_proj_w = (const float*)d_in[16];
    const float* p2_proj_b = (const float*)d_in[17];
    const float* p2_ln1_g  = (const float*)d_in[18];
    const float* p2_ln1_b  = (const float*)d_in[19];
    const float* p2_ln2_g  = (const float*)d_in[20];
    const float* p2_ln2_b  = (const float*)d_in[21];
    const float* p2_m1_w   = (const float*)d_in[22];
    const float* p2_m1_b   = (const float*)d_in[23];
    const float* p2_m2_w   = (const float*)d_in[24];
    const float* p2_m2_b   = (const float*)d_in[25];
    const float* p2_rf     = (const float*)d_in[26];
    const float* proj_w    = (const float*)d_in[27];
    const float* proj_b    = (const float*)d_in[28];

    float* ws = (float*)d_ws;
    size_t off = 0;
    float* ksum1 = ws + off; off += (size_t)NB * 32;
    float* kptv1 = ws + off; off += (size_t)NB * 64 * 32;
    float* ksum2 = ws + off; off += (size_t)NB * 32;
    float* kptv2 = ws + off; off += (size_t)NB * 64 * 32;
    float* s2v = ws + off; off += 192;      // zeroed region: prep_sums atomics
    float* s3v = ws + off; off += 192;
    float* s2v1 = ws + off; off += 192;
    float* s3v1 = ws + off; off += 192;
    const size_t zero_bytes = off * sizeof(float);
    float* kp1 = ws + off; off += (size_t)NB * T1 * 32;
    float* qp1 = ws + off; off += (size_t)NB * T1 * 32;
    float* v1  = ws + off; off += (size_t)NB * T1 * 64;
    float* o1  = ws + off; off += (size_t)NB * T1 * 64;
    unsigned short* wt1h = (unsigned short*)(ws + off); off += (size_t)192 * KP1 / 2;
    unsigned short* wt1l = (unsigned short*)(ws + off); off += (size_t)192 * KP1 / 2;
    unsigned short* wt2h = (unsigned short*)(ws + off); off += (size_t)192 * 576 / 2;
    unsigned short* wt2l = (unsigned short*)(ws + off); off += (size_t)192 * 576 / 2;
    unsigned short* wtfh = (unsigned short*)(ws + off); off += (size_t)768 * 576 / 2;
    unsigned short* wtfl = (unsigned short*)(ws + off); off += (size_t)768 * 576 / 2;
    unsigned short* rf1h = (unsigned short*)(ws + off); off += 1024;
    unsigned short* rf1l = (unsigned short*)(ws + off); off += 1024;
    unsigned short* rf2h = (unsigned short*)(ws + off); off += 1024;
    unsigned short* rf2l = (unsigned short*)(ws + off); off += 1024;
    unsigned short* ep1[6]; unsigned short* ep2[6];
    for (int i = 0; i < 6; ++i) { ep1[i] = (unsigned short*)(ws + off); off += 2048; }
    for (int i = 0; i < 6; ++i) { ep2[i] = (unsigned short*)(ws + off); off += 2048; }
    size_t off2 = 0;
    float* kp2 = kp1 + off2; off2 += (size_t)NB * T2 * 32;
    float* qp2 = kp1 + off2; off2 += (size_t)NB * T2 * 32;
    float* v2  = kp1 + off2; off2 += (size_t)NB * T2 * 64;
    float* o2  = kp1 + off2; off2 += (size_t)NB * T2 * 64;

    hipMemsetAsync(ws, 0, zero_bytes, stream);

    prep_sums<<<(D2 + 15) / 16, 192, 0, stream>>>(p2_kqv_w, p2_ln1_g, p2_ln1_b, p2_kqv_b, s2v, s3v, D2);
    prep_sums<<<(D1 + 15) / 16, 192, 0, stream>>>(p1_kqv_w, p1_ln1_g, p1_ln1_b, p1_kqv_b, s2v1, s3v1, D1);
    prep_wt<<<(192 * KP1 + 255) / 256, 256, 0, stream>>>(p1_kqv_w, p1_ln1_g, wt1h, wt1l, D1, KP1, 192);
    prep_wt<<<(192 * 576 + 255) / 256, 256, 0, stream>>>(p2_kqv_w, p2_ln1_g, wt2h, wt2l, D2, 576, 192);
    prep_wt<<<(768 * 576 + 255) / 256, 256, 0, stream>>>(proj_w, nullptr, wtfh, wtfl, D2, 576, 768);
    prep_rf<<<8, 256, 0, stream>>>(p1_rf, rf1h, rf1l);
    prep_rf<<<8, 256, 0, stream>>>(p2_rf, rf2h, rf2l);
    prep_wt<<<16, 256, 0, stream>>>(p1_proj_w, nullptr, ep1[0], ep1[1], 64, 64, 64);
    prep_wt<<<16, 256, 0, stream>>>(p1_m1_w,   nullptr, ep1[2], ep1[3], 64, 64, 64);
    prep_wt<<<16, 256, 0, stream>>>(p1_m2_w,   nullptr, ep1[4], ep1[5], 64, 64, 64);
    prep_wt<<<16, 256, 0, stream>>>(p2_proj_w, nullptr, ep2[0], ep2[1], 64, 64, 64);
    prep_wt<<<16, 256, 0, stream>>>(p2_m1_w,   nullptr, ep2[2], ep2[3], 64, 64, 64);
    prep_wt<<<16, 256, 0, stream>>>(p2_m2_w,   nullptr, ep2[4], ep2[5], 64, 64, 64);

    front1<<<NB * T1 / 32, 256, 0, stream>>>(x, wt1h, wt1l, s2v1, s3v1, rf1h, rf1l, kp1, qp1, v1);
    reduce_kv<T1, 14><<<NB * 14, 256, 0, stream>>>(kp1, v1, ksum1, kptv1);
    epilogue<T1><<<NB * T1 / 32, 128, 0, stream>>>(qp1, v1, ksum1, kptv1,
                                                   ep1[0], ep1[1], p1_proj_b, p1_ln2_g, p1_ln2_b,
                                                   ep1[2], ep1[3], p1_m1_b, ep1[4], ep1[5], p1_m2_b, o1);
    front2<<<NB * T2 / 16, 128, 0, stream>>>(o1, wt2h, wt2l, s2v, s3v, rf2h, rf2l, kp2, qp2, v2);
    reduce_kv<T2, 7><<<NB * 7, 256, 0, stream>>>(kp2, v2, ksum2, kptv2);
    epilogue<T2><<<NB * T2 / 32, 128, 0, stream>>>(qp2, v2, ksum2, kptv2,
                                                   ep2[0], ep2[1], p2_proj_b, p2_ln2_g, p2_ln2_b,
                                                   ep2[2], ep2[3], p2_m1_b, ep2[4], ep2[5], p2_m2_b, o2);
    final_proj<<<NB * T3 / 16, 256, 0, stream>>>(o2, wtfh, wtfl, proj_b, (float*)d_out);
}

// Round 13
// 684.497 us; speedup vs baseline: 1.4349x; 1.1016x over previous
//
#include <hip/hip_runtime.h>
#include <hip/hip_bf16.h>

#define NB 64
#define T1 3136
#define T2 784
#define T3 196
#define D1 147
#define D2 576

#define KP1 160   // padded K for front1 W^T (147 -> 160)
#define KS1 168   // front1 LDS A row stride (bf16)
#define KS2 584   // front2/final LDS A row stride (bf16)
#define KQ2 72    // kq/epilogue bf16 row stride (144B, 16B-aligned)

typedef __attribute__((ext_vector_type(8))) short bf16x8;
typedef __attribute__((ext_vector_type(4))) float f32x4;

__device__ __forceinline__ unsigned short f2bf(float v) {
    unsigned int u = __float_as_uint(v);
    return (unsigned short)((u + 0x7FFFu + ((u >> 16) & 1u)) >> 16);
}

__device__ __forceinline__ float waveReduceSum(float v) {
#pragma unroll
    for (int off = 32; off > 0; off >>= 1) v += __shfl_down(v, off, 64);
    return __shfl(v, 0, 64);
}

// ---------------------------------------------------------------------------
// prep_sums (parallel, 16-row chunks + atomics into pre-zeroed s2/s3).
// prep_wt: split-bf16 W^T in PACKED tile layout (1KB per (16-col tile, 32-K)).
// prep_rf: same packing for rf (N=32, K=64).
// ---------------------------------------------------------------------------
__global__ __launch_bounds__(192) void prep_sums(
    const float* __restrict__ w, const float* __restrict__ g,
    const float* __restrict__ bb, const float* __restrict__ kqvb,
    float* __restrict__ s2, float* __restrict__ s3, int D)
{
    const int col = threadIdx.x;
    const int d0 = blockIdx.x * 16;
    const int d1 = (d0 + 16 < D) ? d0 + 16 : D;
    float a2 = 0.f, a3 = 0.f;
    for (int d = d0; d < d1; ++d) {
        const float wv = w[d * 192 + col];
        a2 += wv * g[d];
        a3 += wv * bb[d];
    }
    if (blockIdx.x == 0) a3 += kqvb[col];
    atomicAdd(&s2[col], a2);
    atomicAdd(&s3[col], a3);
}

__global__ __launch_bounds__(256) void prep_wt(
    const float* __restrict__ w, const float* __restrict__ g,
    unsigned short* __restrict__ hi, unsigned short* __restrict__ lo,
    int D, int K, int N)
{
    const int i = blockIdx.x * 256 + threadIdx.x;
    if (i >= N * K) return;
    const int n = i / K, k = i % K;
    const float v = (k < D) ? w[k * N + n] * (g ? g[k] : 1.f) : 0.f;
    const unsigned short h = f2bf(v);
    const float hf = __uint_as_float((unsigned int)h << 16);
    const size_t pidx = (size_t)((n >> 4) * (K >> 5) + (k >> 5)) * 512
                      + (size_t)((((k >> 3) & 3) * 16 + (n & 15)) * 8 + (k & 7));
    hi[pidx] = h;
    lo[pidx] = f2bf(v - hf);
}

__global__ __launch_bounds__(256) void prep_rf(
    const float* __restrict__ rf,              // (32,64) row n, col k
    unsigned short* __restrict__ hi, unsigned short* __restrict__ lo)
{
    const int i = blockIdx.x * 256 + threadIdx.x;
    if (i >= 2048) return;
    const int n = i >> 6, k = i & 63;
    const float v = rf[i];
    const unsigned short h = f2bf(v);
    const float hf = __uint_as_float((unsigned int)h << 16);
    const int pidx = ((n >> 4) * 2 + (k >> 5)) * 512
                   + ((((k >> 3) & 3) * 16 + (n & 15)) * 8 + (k & 7));
    hi[pidx] = h;
    lo[pidx] = f2bf(v - hf);
}

// ---------------------------------------------------------------------------
// front1 v8 (full MFMA): 32 tokens, 256 thr = 4 waves.
// ---------------------------------------------------------------------------
__global__ __launch_bounds__(256) void front1(
    const float* __restrict__ x,
    const unsigned short* __restrict__ wt_hi,  // packed (192,KP1)
    const unsigned short* __restrict__ wt_lo,
    const float* __restrict__ s2v, const float* __restrict__ s3v,
    const unsigned short* __restrict__ rf_hi,  // packed (32,64)
    const unsigned short* __restrict__ rf_lo,
    float* __restrict__ kp, float* __restrict__ qp,
    float* __restrict__ v_out)
{
    const int tok0 = blockIdx.x * 32;
    const int b = tok0 / T1;
    const int tbase = tok0 % T1;
    const int tid = threadIdx.x;
    const int wv = tid >> 6, l = tid & 63;
    const int l15 = l & 15, lg = l >> 4;

    __shared__ __align__(16) unsigned short Abuf[2 * 32 * KS1];  // 21504B
    __shared__ float ps_sum[256], ps_sq[256];
    __shared__ float mu_s[32], rs_s[32], xd_s[64];

    unsigned short* A_hi = Abuf;
    unsigned short* A_lo = Abuf + 32 * KS1;
    unsigned short* kqh = Abuf;                // [64][KQ2], aliases post-barrier B
    unsigned short* kql = Abuf + 64 * KQ2;

    // --- fill: m = tid>>3 (token), j = tid&7 (d-slice) ---
    { const int m = tid >> 3, j = tid & 7;
      const int t = tbase + m;
      const int py = t / 56, px = t % 56;
      const int iy0 = py * 4 - 2, ix0 = px * 4 - 2;
      float sm = 0.f, sq = 0.f;
      for (int d = j; d < KS1; d += 8) {
          float val = 0.f;
          if (d < D1) {
              const int cc = d / 49, r = d % 49, ki = r / 7, kj = r % 7;
              const int iy = iy0 + ki, ix = ix0 + kj;
              if (iy >= 0 && iy < 224 && ix >= 0 && ix < 224)
                  val = x[((b * 3 + cc) * 224 + iy) * 224 + ix];
          }
          sm += val; sq += val * val;
          const unsigned short h = f2bf(val);
          A_hi[m * KS1 + d] = h;
          A_lo[m * KS1 + d] = f2bf(val - __uint_as_float((unsigned int)h << 16));
      }
      ps_sum[tid] = sm; ps_sq[tid] = sq; }
    __syncthreads();                           // barrier A
    if (tid < 32) {
        float s = 0.f, s2 = 0.f;
#pragma unroll
        for (int j2 = 0; j2 < 8; ++j2) { s += ps_sum[tid*8+j2]; s2 += ps_sq[tid*8+j2]; }
        const float mu = s * (1.f / D1);
        mu_s[tid] = mu; rs_s[tid] = rsqrtf(s2 * (1.f / D1) - mu * mu + 1e-5f);
    }

    // --- MFMA matvec: wave wv owns N-tiles {3wv..3wv+2} x M-tiles {0,1} ---
    f32x4 acc[2][3];
    { const f32x4 z = {0.f, 0.f, 0.f, 0.f};
#pragma unroll
      for (int mt = 0; mt < 2; ++mt)
#pragma unroll
        for (int nt = 0; nt < 3; ++nt) acc[mt][nt] = z; }

    for (int ks = 0; ks < 5; ++ks) {
        const int ko = ks * 32 + 8 * lg;
        const bf16x8 ah0 = *(const bf16x8*)&A_hi[l15 * KS1 + ko];
        const bf16x8 ah1 = *(const bf16x8*)&A_hi[(16 + l15) * KS1 + ko];
        const bf16x8 al0 = *(const bf16x8*)&A_lo[l15 * KS1 + ko];
        const bf16x8 al1 = *(const bf16x8*)&A_lo[(16 + l15) * KS1 + ko];
#pragma unroll
        for (int nt = 0; nt < 3; ++nt) {
            const size_t wo = ((size_t)((3 * wv + nt) * 5 + ks) << 9) + (size_t)(l << 3);
            const bf16x8 bh = *(const bf16x8*)&wt_hi[wo];
            const bf16x8 bl = *(const bf16x8*)&wt_lo[wo];
            acc[0][nt] = __builtin_amdgcn_mfma_f32_16x16x32_bf16(ah0, bh, acc[0][nt], 0, 0, 0);
            acc[1][nt] = __builtin_amdgcn_mfma_f32_16x16x32_bf16(ah1, bh, acc[1][nt], 0, 0, 0);
            acc[0][nt] = __builtin_amdgcn_mfma_f32_16x16x32_bf16(al0, bh, acc[0][nt], 0, 0, 0);
            acc[1][nt] = __builtin_amdgcn_mfma_f32_16x16x32_bf16(al1, bh, acc[1][nt], 0, 0, 0);
            acc[0][nt] = __builtin_amdgcn_mfma_f32_16x16x32_bf16(ah0, bl, acc[0][nt], 0, 0, 0);
            acc[1][nt] = __builtin_amdgcn_mfma_f32_16x16x32_bf16(ah1, bl, acc[1][nt], 0, 0, 0);
        }
    }
    __syncthreads();                           // barrier B: Abuf dead, mu_s ready

    // --- fold-correction + scatter (kq -> bf16 split LDS, v -> global) ---
    float xk[2][4], xq[2][4];
#pragma unroll
    for (int mt = 0; mt < 2; ++mt)
#pragma unroll
        for (int r = 0; r < 4; ++r) { xk[mt][r] = 0.f; xq[mt][r] = 0.f; }

#pragma unroll
    for (int nt = 0; nt < 3; ++nt) {
        const int col = 48 * wv + 16 * nt + l15;
        const int third = col >> 6, cc = col & 63;
        const float s2c = s2v[col], s3c = s3v[col];
#pragma unroll
        for (int mt = 0; mt < 2; ++mt) {
#pragma unroll
            for (int r = 0; r < 4; ++r) {
                const int token = mt * 16 + 4 * lg + r;
                const float o = rs_s[token] * (acc[mt][nt][r] - mu_s[token] * s2c) + s3c;
                if (third == 2) {
                    v_out[(size_t)(tok0 + token) * 64 + cc] = o;
                } else {
                    const int row = third * 32 + token;
                    const unsigned short h = f2bf(o);
                    kqh[row * KQ2 + cc] = h;
                    kql[row * KQ2 + cc] = f2bf(o - __uint_as_float((unsigned int)h << 16));
                    if (third == 0) xk[mt][r] += o * o; else xq[mt][r] += o * o;
                }
            }
        }
    }
#pragma unroll
    for (int mt = 0; mt < 2; ++mt) {
#pragma unroll
        for (int r = 0; r < 4; ++r) {
            float a = xk[mt][r], q2 = xq[mt][r];
#pragma unroll
            for (int off = 1; off < 16; off <<= 1) {
                a  += __shfl_xor(a,  off, 64);
                q2 += __shfl_xor(q2, off, 64);
            }
            if (l15 == 0) {
                const int token = mt * 16 + 4 * lg + r;
                ps_sum[wv * 64 + token]      = a;
                ps_sum[wv * 64 + 32 + token] = q2;
            }
        }
    }
    __syncthreads();                           // barrier C
    if (tid < 64)
        xd_s[tid] = 0.5f * (ps_sum[tid] + ps_sum[64+tid] + ps_sum[128+tid] + ps_sum[192+tid]);
    __syncthreads();                           // barrier D

    // --- prm_exp via MFMA: A = kq[64][64], B = rf[32][64]; wave wv = M-tile ---
    f32x4 pacc[2];
    { const f32x4 z = {0.f, 0.f, 0.f, 0.f}; pacc[0] = z; pacc[1] = z; }
#pragma unroll
    for (int ks = 0; ks < 2; ++ks) {
        const int ko = ks * 32 + 8 * lg;
        const bf16x8 ah = *(const bf16x8*)&kqh[(16 * wv + l15) * KQ2 + ko];
        const bf16x8 al = *(const bf16x8*)&kql[(16 * wv + l15) * KQ2 + ko];
#pragma unroll
        for (int nt = 0; nt < 2; ++nt) {
            const int wo = (nt * 2 + ks) * 512 + l * 8;
            const bf16x8 bh = *(const bf16x8*)&rf_hi[wo];
            const bf16x8 bl = *(const bf16x8*)&rf_lo[wo];
            pacc[nt] = __builtin_amdgcn_mfma_f32_16x16x32_bf16(ah, bh, pacc[nt], 0, 0, 0);
            pacc[nt] = __builtin_amdgcn_mfma_f32_16x16x32_bf16(al, bh, pacc[nt], 0, 0, 0);
            pacc[nt] = __builtin_amdgcn_mfma_f32_16x16x32_bf16(ah, bl, pacc[nt], 0, 0, 0);
        }
    }
#pragma unroll
    for (int nt = 0; nt < 2; ++nt) {
#pragma unroll
        for (int r = 0; r < 4; ++r) {
            const int row = 16 * wv + 4 * lg + r;
            const int half = row >> 5, token = row & 31;
            const float p = expf(pacc[nt][r] - xd_s[row]) * 0.1767766952966369f;
            (half ? qp : kp)[(size_t)(tok0 + token) * 32 + nt * 16 + l15] = p;
        }
    }
}

// ---------------------------------------------------------------------------
// front2 v7 (4-wave): 16 tokens, 256 thr = 4 waves. R12's 2-wave version was
// latency-starved (VALU 13%, MFMA 8%, occ 18.5%: 4 blocks/CU x 2 waves =
// ~1.5 waves/SIMD against ~200cyc L2 B-loads). Same 16-token tile + shared
// A staging (LDS unchanged -> still 4 blocks/CU) but 4 waves: wave wv owns
// N-tiles {3wv..3wv+2}; waves/CU 8 -> 16 (50% cap); per-wave B-loads halve.
// prm_exp splits (M-tile, rf-half) across the 4 waves.
// ---------------------------------------------------------------------------
__global__ __launch_bounds__(256) void front2(
    const float* __restrict__ src,             // o1 (B*T1,64)
    const unsigned short* __restrict__ wt_hi,  // packed (192,576)
    const unsigned short* __restrict__ wt_lo,
    const float* __restrict__ s2v, const float* __restrict__ s3v,
    const unsigned short* __restrict__ rf_hi,
    const unsigned short* __restrict__ rf_lo,
    float* __restrict__ kp, float* __restrict__ qp,
    float* __restrict__ v_out)
{
    const int tok0 = blockIdx.x * 16;
    const int b = tok0 / T2;
    const int tbase = tok0 % T2;
    const int tid = threadIdx.x;
    const int wv = tid >> 6, l = tid & 63;
    const int l15 = l & 15, lg = l >> 4;

    __shared__ __align__(16) unsigned short Abuf[2 * 16 * KS2];  // 37376B
    __shared__ float ps_sum[256], ps_sq[256];
    __shared__ float mu_s[16], rs_s[16], xd_s[32];

    unsigned short* A_hi = Abuf;
    unsigned short* A_lo = Abuf + 16 * KS2;
    unsigned short* kqh = Abuf;                // [32][KQ2]
    unsigned short* kql = Abuf + 32 * KQ2;

    // --- fill: thread owns (token g16 = tid>>4, ch = tid&15); 36 values ---
    { const int g16 = tid >> 4, ch = tid & 15;
      const int tmine = tbase + g16;
      const int py = tmine / 28, px = tmine % 28;
      const int iy0 = py * 2 - 1, ix0 = px * 2 - 1;
      const float* srcb = src + (size_t)b * T1 * 64 + ch;
      unsigned short* Ah = &A_hi[g16 * KS2];
      unsigned short* Al = &A_lo[g16 * KS2];
      float sm = 0.f, sq = 0.f;
#pragma unroll
      for (int r = 0; r < 9; ++r) {
          const int iy = iy0 + r / 3, ix = ix0 + r % 3;
          const bool ok = (iy >= 0 && iy < 56 && ix >= 0 && ix < 56);
          const float* sp = srcb + (size_t)(iy * 56 + ix) * 64;
#pragma unroll
          for (int c = 0; c < 4; ++c) {
              const float val = ok ? sp[c * 16] : 0.f;
              sm += val; sq += val * val;
              const int d = (c * 16 + ch) * 9 + r;
              const unsigned short h = f2bf(val);
              Ah[d] = h;
              Al[d] = f2bf(val - __uint_as_float((unsigned int)h << 16));
          }
      }
      ps_sum[tid] = sm; ps_sq[tid] = sq; }
    __syncthreads();                           // barrier A
    if (tid < 16) {
        float s = 0.f, s2 = 0.f;
#pragma unroll
        for (int j = 0; j < 16; ++j) { s += ps_sum[tid*16+j]; s2 += ps_sq[tid*16+j]; }
        const float mu = s * (1.f / D2);
        mu_s[tid] = mu; rs_s[tid] = rsqrtf(s2 * (1.f / D2) - mu * mu + 1e-5f);
    }

    // --- MFMA: wave wv owns N-tiles {3wv..3wv+2} (cols 48wv..48wv+47) ---
    f32x4 acc[3];
    { const f32x4 z = {0.f, 0.f, 0.f, 0.f};
#pragma unroll
      for (int nt = 0; nt < 3; ++nt) acc[nt] = z; }

    for (int ks = 0; ks < 18; ++ks) {
        const int ko = ks * 32 + 8 * lg;
        const bf16x8 ah = *(const bf16x8*)&A_hi[l15 * KS2 + ko];
        const bf16x8 al = *(const bf16x8*)&A_lo[l15 * KS2 + ko];
#pragma unroll
        for (int nt = 0; nt < 3; ++nt) {
            const size_t wo = ((size_t)((3 * wv + nt) * 18 + ks) << 9) + (size_t)(l << 3);
            const bf16x8 bh = *(const bf16x8*)&wt_hi[wo];
            const bf16x8 bl = *(const bf16x8*)&wt_lo[wo];
            acc[nt] = __builtin_amdgcn_mfma_f32_16x16x32_bf16(ah, bh, acc[nt], 0, 0, 0);
            acc[nt] = __builtin_amdgcn_mfma_f32_16x16x32_bf16(al, bh, acc[nt], 0, 0, 0);
            acc[nt] = __builtin_amdgcn_mfma_f32_16x16x32_bf16(ah, bl, acc[nt], 0, 0, 0);
        }
    }
    __syncthreads();                           // barrier B: Abuf dead, mu_s ready

    // --- fold-correction + scatter ---
    float xk[4], xq[4];
#pragma unroll
    for (int r = 0; r < 4; ++r) { xk[r] = 0.f; xq[r] = 0.f; }

#pragma unroll
    for (int nt = 0; nt < 3; ++nt) {
        const int col = 48 * wv + 16 * nt + l15;
        const int third = col >> 6, cc = col & 63;
        const float s2c = s2v[col], s3c = s3v[col];
#pragma unroll
        for (int r = 0; r < 4; ++r) {
            const int token = 4 * lg + r;
            const float o = rs_s[token] * (acc[nt][r] - mu_s[token] * s2c) + s3c;
            if (third == 2) {
                v_out[(size_t)(tok0 + token) * 64 + cc] = o;
            } else {
                const int row = third * 16 + token;
                const unsigned short h = f2bf(o);
                kqh[row * KQ2 + cc] = h;
                kql[row * KQ2 + cc] = f2bf(o - __uint_as_float((unsigned int)h << 16));
                if (third == 0) xk[r] += o * o; else xq[r] += o * o;
            }
        }
    }
    // per-wave xd partials at ps_sum[wv*64 + row], row = third*16 + token
#pragma unroll
    for (int r = 0; r < 4; ++r) {
        float a = xk[r], q2 = xq[r];
#pragma unroll
        for (int off = 1; off < 16; off <<= 1) {
            a  += __shfl_xor(a,  off, 64);
            q2 += __shfl_xor(q2, off, 64);
        }
        if (l15 == 0) {
            const int token = 4 * lg + r;
            ps_sum[wv * 64 + token]      = a;    // k rows 0..15
            ps_sum[wv * 64 + 16 + token] = q2;   // q rows 16..31
        }
    }
    __syncthreads();                           // barrier C
    if (tid < 32)
        xd_s[tid] = 0.5f * (ps_sum[tid] + ps_sum[64+tid] + ps_sum[128+tid] + ps_sum[192+tid]);
    __syncthreads();                           // barrier D

    // --- prm_exp via MFMA: A = kq[32][64], B = rf[32][64].
    //     wave wv: M-tile mt = wv>>1 (rows 16mt..16mt+15), rf-half ntp = wv&1.
    const int mt = wv >> 1, ntp = wv & 1;
    f32x4 pacc;
    { const f32x4 z = {0.f, 0.f, 0.f, 0.f}; pacc = z; }
#pragma unroll
    for (int ks = 0; ks < 2; ++ks) {
        const int ko = ks * 32 + 8 * lg;
        const bf16x8 ah = *(const bf16x8*)&kqh[(16 * mt + l15) * KQ2 + ko];
        const bf16x8 al = *(const bf16x8*)&kql[(16 * mt + l15) * KQ2 + ko];
        const int wo = (ntp * 2 + ks) * 512 + l * 8;
        const bf16x8 bh = *(const bf16x8*)&rf_hi[wo];
        const bf16x8 bl = *(const bf16x8*)&rf_lo[wo];
        pacc = __builtin_amdgcn_mfma_f32_16x16x32_bf16(ah, bh, pacc, 0, 0, 0);
        pacc = __builtin_amdgcn_mfma_f32_16x16x32_bf16(al, bh, pacc, 0, 0, 0);
        pacc = __builtin_amdgcn_mfma_f32_16x16x32_bf16(ah, bl, pacc, 0, 0, 0);
    }
#pragma unroll
    for (int r = 0; r < 4; ++r) {
        const int row = 16 * mt + 4 * lg + r;
        const int half = row >> 4, token = row & 15;
        const float p = expf(pacc[r] - xd_s[row]) * 0.1767766952966369f;
        (half ? qp : kp)[(size_t)(tok0 + token) * 32 + ntp * 16 + l15] = p;
    }
}

// ---------------------------------------------------------------------------
// reduce_kv, split S-ways over T with atomics (ksum/kptv pre-zeroed)
// ---------------------------------------------------------------------------
template <int T, int S>
__global__ __launch_bounds__(256) void reduce_kv(
    const float* __restrict__ kp, const float* __restrict__ v,
    float* __restrict__ ksum, float* __restrict__ kptv)
{
    const int b = blockIdx.x / S, s = blockIdx.x % S;
    const int chunk = T / S;
    const int tid = threadIdx.x;
    __shared__ float kp_s[8][32];
    __shared__ float v_s[8][64];
    float acc[8] = {0.f, 0.f, 0.f, 0.f, 0.f, 0.f, 0.f, 0.f};
    float ks = 0.f;
    const int n = tid >> 2;
    const int mb = (tid & 3) * 8;
    const float* kpb = kp + (size_t)b * T * 32;
    const float* vb  = v  + (size_t)b * T * 64;

    for (int t0 = s * chunk; t0 < (s + 1) * chunk; t0 += 8) {
        kp_s[tid >> 5][tid & 31] = kpb[(t0 + (tid >> 5)) * 32 + (tid & 31)];
        {
            const int i0 = tid * 2, i1 = tid * 2 + 1;
            v_s[i0 >> 6][i0 & 63] = vb[(t0 + (i0 >> 6)) * 64 + (i0 & 63)];
            v_s[i1 >> 6][i1 & 63] = vb[(t0 + (i1 >> 6)) * 64 + (i1 & 63)];
        }
        __syncthreads();
#pragma unroll
        for (int tt = 0; tt < 8; ++tt) {
            const float vv = v_s[tt][n];
#pragma unroll
            for (int i = 0; i < 8; ++i) acc[i] += vv * kp_s[tt][mb + i];
        }
        if (tid < 32) {
#pragma unroll
            for (int tt = 0; tt < 8; ++tt) ks += kp_s[tt][tid];
        }
        __syncthreads();
    }
#pragma unroll
    for (int i = 0; i < 8; ++i) atomicAdd(&kptv[(b * 64 + n) * 32 + mb + i], acc[i]);
    if (tid < 32) atomicAdd(&ksum[b * 32 + tid], ks);
}

// ---------------------------------------------------------------------------
// epilogue v2 (MFMA): 128 threads = 2 waves, each wave owns one 16-token tile.
// ---------------------------------------------------------------------------
template <int T>
__global__ __launch_bounds__(128) void epilogue(
    const float* __restrict__ qp, const float* __restrict__ v,
    const float* __restrict__ ksum, const float* __restrict__ kptv,
    const unsigned short* __restrict__ pw_hi, const unsigned short* __restrict__ pw_lo,
    const float* __restrict__ proj_b,
    const float* __restrict__ ln2_g, const float* __restrict__ ln2_b,
    const unsigned short* __restrict__ m1_hi, const unsigned short* __restrict__ m1_lo,
    const float* __restrict__ m1_b,
    const unsigned short* __restrict__ m2_hi, const unsigned short* __restrict__ m2_lo,
    const float* __restrict__ m2_b,
    float* __restrict__ out)
{
    const int sub = threadIdx.x >> 6;
    const int l = threadIdx.x & 63;
    const int l15 = l & 15, lg = l >> 4;
    const int tok0 = blockIdx.x * 32 + sub * 16;
    const int b = tok0 / T;

    __shared__ __align__(16) float qp_s[2][16 * 36];
    __shared__ __align__(16) unsigned short Ah[2][16 * KQ2];
    __shared__ __align__(16) unsigned short Al[2][16 * KQ2];
    __shared__ float ks_s[2][32];
    __shared__ float D_s[2][16];

    for (int idx = l; idx < 512; idx += 64)
        qp_s[sub][(idx >> 5) * 36 + (idx & 31)] = qp[(size_t)tok0 * 32 + idx];
    if (l < 32) ks_s[sub][l] = ksum[b * 32 + l];
    __syncthreads();
    if (l < 16) {
        float D = 1e-8f;
        for (int r = 0; r < 32; ++r) D += qp_s[sub][l * 36 + r] * ks_s[sub][r];
        D_s[sub][l] = D;
    }
    float4 kv4[8];
#pragma unroll
    for (int g = 0; g < 8; ++g)
        kv4[g] = *(const float4*)&kptv[(size_t)(b * 64 + l) * 32 + 4 * g];
    __syncthreads();

    unsigned short* ah = Ah[sub];
    unsigned short* al = Al[sub];
#pragma unroll
    for (int m = 0; m < 16; ++m) {
        const float4* q4 = (const float4*)&qp_s[sub][m * 36];
        float a = 0.f;
#pragma unroll
        for (int g = 0; g < 8; ++g) {
            const float4 qv = q4[g];
            a += qv.x*kv4[g].x + qv.y*kv4[g].y + qv.z*kv4[g].z + qv.w*kv4[g].w;
        }
        a /= D_s[sub][m];
        const unsigned short h = f2bf(a);
        ah[m * KQ2 + l] = h;
        al[m * KQ2 + l] = f2bf(a - __uint_as_float((unsigned int)h << 16));
    }
    __syncthreads();

    f32x4 y[4];
    { const f32x4 z = {0.f, 0.f, 0.f, 0.f};
#pragma unroll
      for (int nt = 0; nt < 4; ++nt) y[nt] = z; }
#pragma unroll
    for (int ks = 0; ks < 2; ++ks) {
        const int ko = ks * 32 + 8 * lg;
        const bf16x8 fa = *(const bf16x8*)&ah[l15 * KQ2 + ko];
        const bf16x8 fl = *(const bf16x8*)&al[l15 * KQ2 + ko];
#pragma unroll
        for (int nt = 0; nt < 4; ++nt) {
            const int wo = (nt * 2 + ks) * 512 + l * 8;
            const bf16x8 bh = *(const bf16x8*)&pw_hi[wo];
            const bf16x8 bl = *(const bf16x8*)&pw_lo[wo];
            y[nt] = __builtin_amdgcn_mfma_f32_16x16x32_bf16(fa, bh, y[nt], 0, 0, 0);
            y[nt] = __builtin_amdgcn_mfma_f32_16x16x32_bf16(fl, bh, y[nt], 0, 0, 0);
            y[nt] = __builtin_amdgcn_mfma_f32_16x16x32_bf16(fa, bl, y[nt], 0, 0, 0);
        }
    }
#pragma unroll
    for (int nt = 0; nt < 4; ++nt) {
        const int col = 16 * nt + l15;
        const float pb = proj_b[col];
#pragma unroll
        for (int r = 0; r < 4; ++r)
            y[nt][r] += pb + v[(size_t)(tok0 + 4 * lg + r) * 64 + col];
    }
    __syncthreads();

    { float g2c[4], b2c[4];
#pragma unroll
      for (int nt = 0; nt < 4; ++nt) { g2c[nt] = ln2_g[16*nt+l15]; b2c[nt] = ln2_b[16*nt+l15]; }
#pragma unroll
      for (int r = 0; r < 4; ++r) {
          float s = y[0][r] + y[1][r] + y[2][r] + y[3][r];
          float s2 = y[0][r]*y[0][r] + y[1][r]*y[1][r] + y[2][r]*y[2][r] + y[3][r]*y[3][r];
#pragma unroll
          for (int off = 1; off < 16; off <<= 1) {
              s  += __shfl_xor(s,  off, 64);
              s2 += __shfl_xor(s2, off, 64);
          }
          const float mu = s * (1.f / 64.f);
          const float rs = rsqrtf(s2 * (1.f / 64.f) - mu * mu + 1e-5f);
          const int row = (4 * lg + r) * KQ2;
#pragma unroll
          for (int nt = 0; nt < 4; ++nt) {
              const float z = (y[nt][r] - mu) * rs * g2c[nt] + b2c[nt];
              const unsigned short h = f2bf(z);
              ah[row + 16 * nt + l15] = h;
              al[row + 16 * nt + l15] = f2bf(z - __uint_as_float((unsigned int)h << 16));
          }
      } }
    __syncthreads();

    f32x4 hf[4];
    { const f32x4 z = {0.f, 0.f, 0.f, 0.f};
#pragma unroll
      for (int nt = 0; nt < 4; ++nt) hf[nt] = z; }
#pragma unroll
    for (int ks = 0; ks < 2; ++ks) {
        const int ko = ks * 32 + 8 * lg;
        const bf16x8 fa = *(const bf16x8*)&ah[l15 * KQ2 + ko];
        const bf16x8 fl = *(const bf16x8*)&al[l15 * KQ2 + ko];
#pragma unroll
        for (int nt = 0; nt < 4; ++nt) {
            const int wo = (nt * 2 + ks) * 512 + l * 8;
            const bf16x8 bh = *(const bf16x8*)&m1_hi[wo];
            const bf16x8 bl = *(const bf16x8*)&m1_lo[wo];
            hf[nt] = __builtin_amdgcn_mfma_f32_16x16x32_bf16(fa, bh, hf[nt], 0, 0, 0);
            hf[nt] = __builtin_amdgcn_mfma_f32_16x16x32_bf16(fl, bh, hf[nt], 0, 0, 0);
            hf[nt] = __builtin_amdgcn_mfma_f32_16x16x32_bf16(fa, bl, hf[nt], 0, 0, 0);
        }
    }
    __syncthreads();
#pragma unroll
    for (int nt = 0; nt < 4; ++nt) {
        const float b1 = m1_b[16 * nt + l15];
#pragma unroll
        for (int r = 0; r < 4; ++r) {
            const float t = hf[nt][r] + b1;
            const float gl = 0.5f * t * (1.f + erff(t * 0.7071067811865476f));
            const unsigned short h = f2bf(gl);
            const int idx = (4 * lg + r) * KQ2 + 16 * nt + l15;
            ah[idx] = h;
            al[idx] = f2bf(gl - __uint_as_float((unsigned int)h << 16));
        }
    }
    __syncthreads();

    f32x4 oacc[4];
    { const f32x4 z = {0.f, 0.f, 0.f, 0.f};
#pragma unroll
      for (int nt = 0; nt < 4; ++nt) oacc[nt] = z; }
#pragma unroll
    for (int ks = 0; ks < 2; ++ks) {
        const int ko = ks * 32 + 8 * lg;
        const bf16x8 fa = *(const bf16x8*)&ah[l15 * KQ2 + ko];
        const bf16x8 fl = *(const bf16x8*)&al[l15 * KQ2 + ko];
#pragma unroll
        for (int nt = 0; nt < 4; ++nt) {
            const int wo = (nt * 2 + ks) * 512 + l * 8;
            const bf16x8 bh = *(const bf16x8*)&m2_hi[wo];
            const bf16x8 bl = *(const bf16x8*)&m2_lo[wo];
            oacc[nt] = __builtin_amdgcn_mfma_f32_16x16x32_bf16(fa, bh, oacc[nt], 0, 0, 0);
            oacc[nt] = __builtin_amdgcn_mfma_f32_16x16x32_bf16(fl, bh, oacc[nt], 0, 0, 0);
            oacc[nt] = __builtin_amdgcn_mfma_f32_16x16x32_bf16(fa, bl, oacc[nt], 0, 0, 0);
        }
    }
#pragma unroll
    for (int nt = 0; nt < 4; ++nt) {
        const int col = 16 * nt + l15;
        const float b2v = m2_b[col];
#pragma unroll
        for (int r = 0; r < 4; ++r)
            out[(size_t)(tok0 + 4 * lg + r) * 64 + col] = y[nt][r] + oacc[nt][r] + b2v;
    }
}

// ---------------------------------------------------------------------------
// final_proj v2 (MFMA): 16 tokens, 256 thr = 4 waves.
// ---------------------------------------------------------------------------
__global__ __launch_bounds__(256) void final_proj(
    const float* __restrict__ o2,              // (B*T2,64)
    const unsigned short* __restrict__ wt_hi,  // packed (768,576)
    const unsigned short* __restrict__ wt_lo,
    const float* __restrict__ bias,            // (768)
    float* __restrict__ out)                   // (B*T3,768)
{
    const int tok0 = blockIdx.x * 16;
    const int tid = threadIdx.x;
    const int wv = tid >> 6, l = tid & 63;
    const int l15 = l & 15, lg = l >> 4;

    __shared__ __align__(16) unsigned short Abuf[2 * 16 * KS2];  // 37376B
    unsigned short* A_hi = Abuf;
    unsigned short* A_lo = Abuf + 16 * KS2;

    { const int cl = tid & 15, grp = tid >> 4;
      for (int k = 0; k < 4; ++k) {
#pragma unroll
        for (int ii = 0; ii < 9; ++ii) {
            const int u = grp + ii * 16;       // u = m*9 + r
            const int m = u / 9, r = u % 9;
            const int tok = tok0 + m, bb = tok / T3, tt = tok % T3;
            const int py = tt / 14, px = tt % 14;
            const int iy = py * 2 - 1 + r / 3, ix = px * 2 - 1 + r % 3;
            float val = 0.f;
            if (iy >= 0 && iy < 28 && ix >= 0 && ix < 28)
                val = o2[(size_t)(bb * T2 + iy * 28 + ix) * 64 + k * 16 + cl];
            const int d = k * 144 + cl * 9 + r;
            const unsigned short h = f2bf(val);
            A_hi[m * KS2 + d] = h;
            A_lo[m * KS2 + d] = f2bf(val - __uint_as_float((unsigned int)h << 16));
        }
      }
    }
    __syncthreads();

    f32x4 acc[12];
    { const f32x4 z = {0.f, 0.f, 0.f, 0.f};
#pragma unroll
      for (int nt = 0; nt < 12; ++nt) acc[nt] = z; }

    for (int ks = 0; ks < 18; ++ks) {
        const int ko = ks * 32 + 8 * lg;
        const bf16x8 ah = *(const bf16x8*)&A_hi[l15 * KS2 + ko];
        const bf16x8 al = *(const bf16x8*)&A_lo[l15 * KS2 + ko];
#pragma unroll
        for (int nt = 0; nt < 12; ++nt) {
            const size_t wo = ((size_t)((12 * wv + nt) * 18 + ks) << 9) + (size_t)(l << 3);
            const bf16x8 bh = *(const bf16x8*)&wt_hi[wo];
            const bf16x8 bl = *(const bf16x8*)&wt_lo[wo];
            acc[nt] = __builtin_amdgcn_mfma_f32_16x16x32_bf16(ah, bh, acc[nt], 0, 0, 0);
            acc[nt] = __builtin_amdgcn_mfma_f32_16x16x32_bf16(al, bh, acc[nt], 0, 0, 0);
            acc[nt] = __builtin_amdgcn_mfma_f32_16x16x32_bf16(ah, bl, acc[nt], 0, 0, 0);
        }
    }

#pragma unroll
    for (int nt = 0; nt < 12; ++nt) {
        const int col = 192 * wv + 16 * nt + l15;
        const float bv = bias[col];
#pragma unroll
        for (int r = 0; r < 4; ++r) {
            const int token = 4 * lg + r;
            out[(size_t)(tok0 + token) * 768 + col] = acc[nt][r] + bv;
        }
    }
}

// ---------------------------------------------------------------------------
extern "C" void kernel_launch(void* const* d_in, const int* in_sizes, int n_in,
                              void* d_out, int out_size, void* d_ws, size_t ws_size,
                              hipStream_t stream) {
    const float* x         = (const float*)d_in[0];
    const float* p1_kqv_w  = (const float*)d_in[1];
    const float* p1_kqv_b  = (const float*)d_in[2];
    const float* p1_proj_w = (const float*)d_in[3];
    const float* p1_proj_b = (const float*)d_in[4];
    const float* p1_ln1_g  = (const float*)d_in[5];
    const float* p1_ln1_b  = (const float*)d_in[6];
    const float* p1_ln2_g  = (const float*)d_in[7];
    const float* p1_ln2_b  = (const float*)d_in[8];
    const float* p1_m1_w   = (const float*)d_in[9];
    const float* p1_m1_b   = (const float*)d_in[10];
    const float* p1_m2_w   = (const float*)d_in[11];
    const float* p1_m2_b   = (const float*)d_in[12];
    const float* p1_rf     = (const float*)d_in[13];
    const float* p2_kqv_w  = (const float*)d_in[14];
    const float* p2_kqv_b  = (const float*)d_in[15];
    const float* p2_proj_w = (const float*)d_in[16];
    const float* p2_proj_b = (const float*)d_in[17];
    const float* p2_ln1_g  = (const float*)d_in[18];
    const float* p2_ln1_b  = (const float*)d_in[19];
    const float* p2_ln2_g  = (const float*)d_in[20];
    const float* p2_ln2_b  = (const float*)d_in[21];
    const float* p2_m1_w   = (const float*)d_in[22];
    const float* p2_m1_b   = (const float*)d_in[23];
    const float* p2_m2_w   = (const float*)d_in[24];
    const float* p2_m2_b   = (const float*)d_in[25];
    const float* p2_rf     = (const float*)d_in[26];
    const float* proj_w    = (const float*)d_in[27];
    const float* proj_b    = (const float*)d_in[28];

    float* ws = (float*)d_ws;
    size_t off = 0;
    float* ksum1 = ws + off; off += (size_t)NB * 32;
    float* kptv1 = ws + off; off += (size_t)NB * 64 * 32;
    float* ksum2 = ws + off; off += (size_t)NB * 32;
    float* kptv2 = ws + off; off += (size_t)NB * 64 * 32;
    float* s2v = ws + off; off += 192;      // zeroed region: prep_sums atomics
    float* s3v = ws + off; off += 192;
    float* s2v1 = ws + off; off += 192;
    float* s3v1 = ws + off; off += 192;
    const size_t zero_bytes = off * sizeof(float);
    float* kp1 = ws + off; off += (size_t)NB * T1 * 32;
    float* qp1 = ws + off; off += (size_t)NB * T1 * 32;
    float* v1  = ws + off; off += (size_t)NB * T1 * 64;
    float* o1  = ws + off; off += (size_t)NB * T1 * 64;
    unsigned short* wt1h = (unsigned short*)(ws + off); off += (size_t)192 * KP1 / 2;
    unsigned short* wt1l = (unsigned short*)(ws + off); off += (size_t)192 * KP1 / 2;
    unsigned short* wt2h = (unsigned short*)(ws + off); off += (size_t)192 * 576 / 2;
    unsigned short* wt2l = (unsigned short*)(ws + off); off += (size_t)192 * 576 / 2;
    unsigned short* wtfh = (unsigned short*)(ws + off); off += (size_t)768 * 576 / 2;
    unsigned short* wtfl = (unsigned short*)(ws + off); off += (size_t)768 * 576 / 2;
    unsigned short* rf1h = (unsigned short*)(ws + off); off += 1024;
    unsigned short* rf1l = (unsigned short*)(ws + off); off += 1024;
    unsigned short* rf2h = (unsigned short*)(ws + off); off += 1024;
    unsigned short* rf2l = (unsigned short*)(ws + off); off += 1024;
    unsigned short* ep1[6]; unsigned short* ep2[6];
    for (int i = 0; i < 6; ++i) { ep1[i] = (unsigned short*)(ws + off); off += 2048; }
    for (int i = 0; i < 6; ++i) { ep2[i] = (unsigned short*)(ws + off); off += 2048; }
    size_t off2 = 0;
    float* kp2 = kp1 + off2; off2 += (size_t)NB * T2 * 32;
    float* qp2 = kp1 + off2; off2 += (size_t)NB * T2 * 32;
    float* v2  = kp1 + off2; off2 += (size_t)NB * T2 * 64;
    float* o2  = kp1 + off2; off2 += (size_t)NB * T2 * 64;

    hipMemsetAsync(ws, 0, zero_bytes, stream);

    prep_sums<<<(D2 + 15) / 16, 192, 0, stream>>>(p2_kqv_w, p2_ln1_g, p2_ln1_b, p2_kqv_b, s2v, s3v, D2);
    prep_sums<<<(D1 + 15) / 16, 192, 0, stream>>>(p1_kqv_w, p1_ln1_g, p1_ln1_b, p1_kqv_b, s2v1, s3v1, D1);
    prep_wt<<<(192 * KP1 + 255) / 256, 256, 0, stream>>>(p1_kqv_w, p1_ln1_g, wt1h, wt1l, D1, KP1, 192);
    prep_wt<<<(192 * 576 + 255) / 256, 256, 0, stream>>>(p2_kqv_w, p2_ln1_g, wt2h, wt2l, D2, 576, 192);
    prep_wt<<<(768 * 576 + 255) / 256, 256, 0, stream>>>(proj_w, nullptr, wtfh, wtfl, D2, 576, 768);
    prep_rf<<<8, 256, 0, stream>>>(p1_rf, rf1h, rf1l);
    prep_rf<<<8, 256, 0, stream>>>(p2_rf, rf2h, rf2l);
    prep_wt<<<16, 256, 0, stream>>>(p1_proj_w, nullptr, ep1[0], ep1[1], 64, 64, 64);
    prep_wt<<<16, 256, 0, stream>>>(p1_m1_w,   nullptr, ep1[2], ep1[3], 64, 64, 64);
    prep_wt<<<16, 256, 0, stream>>>(p1_m2_w,   nullptr, ep1[4], ep1[5], 64, 64, 64);
    prep_wt<<<16, 256, 0, stream>>>(p2_proj_w, nullptr, ep2[0], ep2[1], 64, 64, 64);
    prep_wt<<<16, 256, 0, stream>>>(p2_m1_w,   nullptr, ep2[2], ep2[3], 64, 64, 64);
    prep_wt<<<16, 256, 0, stream>>>(p2_m2_w,   nullptr, ep2[4], ep2[5], 64, 64, 64);

    front1<<<NB * T1 / 32, 256, 0, stream>>>(x, wt1h, wt1l, s2v1, s3v1, rf1h, rf1l, kp1, qp1, v1);
    reduce_kv<T1, 14><<<NB * 14, 256, 0, stream>>>(kp1, v1, ksum1, kptv1);
    epilogue<T1><<<NB * T1 / 32, 128, 0, stream>>>(qp1, v1, ksum1, kptv1,
                                                   ep1[0], ep1[1], p1_proj_b, p1_ln2_g, p1_ln2_b,
                                                   ep1[2], ep1[3], p1_m1_b, ep1[4], ep1[5], p1_m2_b, o1);
    front2<<<NB * T2 / 16, 256, 0, stream>>>(o1, wt2h, wt2l, s2v, s3v, rf2h, rf2l, kp2, qp2, v2);
    reduce_kv<T2, 7><<<NB * 7, 256, 0, stream>>>(kp2, v2, ksum2, kptv2);
    epilogue<T2><<<NB * T2 / 32, 128, 0, stream>>>(qp2, v2, ksum2, kptv2,
                                                   ep2[0], ep2[1], p2_proj_b, p2_ln2_g, p2_ln2_b,
                                                   ep2[2], ep2[3], p2_m1_b, ep2[4], ep2[5], p2_m2_b, o2);
    final_proj<<<NB * T3 / 16, 256, 0, stream>>>(o2, wtfh, wtfl, proj_b, (float*)d_out);
}